// Round 9
// baseline (287.864 us; speedup 1.0000x reference)
//
#include <hip/hip_runtime.h>

typedef unsigned short u16;
typedef unsigned int u32;

typedef __attribute__((ext_vector_type(8))) short short8;
typedef __attribute__((ext_vector_type(4))) float floatx4;

__device__ __forceinline__ float bf2f(u16 u) { return __uint_as_float(((u32)u) << 16); }
__device__ __forceinline__ u16 f2bf(float f) {
    u32 x = __float_as_uint(f);
    x += 0x7fffu + ((x >> 16) & 1u);
    return (u16)(x >> 16);
}
__device__ __forceinline__ void gl_lds16(const void* g, void* l) {
    __builtin_amdgcn_global_load_lds((const __attribute__((address_space(1))) u32*)g,
                                     (__attribute__((address_space(3))) u32*)l, 16, 0, 0);
}

// Fragment-tiled ("swiz") layouts: data grouped in 1024B chunks of [16 rows x 32 k],
// element order = gl_lds16 lane order: u16 off = chunk*512 + (((k>>3)&3)*16 + (row&15))*8 + (k&7).
// A-operands (t, o): chunk = (row>>4)*24 + (k>>5)   [K=768 -> 24 kchunks]
// W-operands (qkv_w, proj_w): same with row=n.
// Q/K-swiz (per bh, n x dh): chunk = (n>>4)*6 + (dh>>5)
// V-swiz (per bh): chunk = (n>>5)*12 + (dh>>4), lane = ((n>>3)&3)*16 + (dh&15), low3 = n&7

// ---------------- fused startup: tpos-transpose | weight cvt | stats zeroing ----------------
// blocks [0,1536): x -> t swiz bf16 + pos ; [1536,2724): weight cvt ; [2724,2836): zero stats
__global__ __launch_bounds__(256) void k_init(const float* __restrict__ x,
                                              const float* __restrict__ pos,
                                              const float* __restrict__ wq,
                                              const float* __restrict__ wp,
                                              const float* __restrict__ wpw,
                                              u16* __restrict__ t,
                                              u16* __restrict__ wout,
                                              float* __restrict__ zbuf) {
    __shared__ float tile[64][65];
    const int bid = blockIdx.x;
    const int tid = threadIdx.x;
    if (bid < 1536) {
        const int cd0 = (bid % 12) * 64;
        const int hw0 = ((bid / 12) & 15) * 64;
        const int b = bid / 192;
#pragma unroll
        for (int i = 0; i < 16; i++) {
            int f = i * 256 + tid;
            int cdl = f >> 6, hwl = f & 63;
            int cd = cd0 + cdl, c = cd >> 3, d = cd & 7;
            tile[cdl][hwl] = x[(size_t)(((b * 96 + c) * 8 + d)) * 1024 + hw0 + hwl];
        }
        __syncthreads();
#pragma unroll
        for (int it = 0; it < 2; it++) {
            int u = it * 256 + tid;       // 512 units of 16B
            int ch = u >> 6, l = u & 63;
            int n16l = ch >> 1, kcl = ch & 1;
            int hwl = n16l * 16 + (l & 15);
            int cdl = kcl * 32 + (l >> 4) * 8;
            int row = b * 1024 + hw0 + hwl;
            int cd = cd0 + cdl;
            const float* pp = pos + (size_t)(hw0 + hwl) * 768 + cd;
            float4 p0 = *(const float4*)pp;
            float4 p1 = *(const float4*)(pp + 4);
            short8 v;
            v[0] = (short)f2bf(tile[cdl + 0][hwl] + p0.x);
            v[1] = (short)f2bf(tile[cdl + 1][hwl] + p0.y);
            v[2] = (short)f2bf(tile[cdl + 2][hwl] + p0.z);
            v[3] = (short)f2bf(tile[cdl + 3][hwl] + p0.w);
            v[4] = (short)f2bf(tile[cdl + 4][hwl] + p1.x);
            v[5] = (short)f2bf(tile[cdl + 5][hwl] + p1.y);
            v[6] = (short)f2bf(tile[cdl + 6][hwl] + p1.z);
            v[7] = (short)f2bf(tile[cdl + 7][hwl] + p1.w);
            size_t chunk = (size_t)(row >> 4) * 24 + (cd >> 5);
            *(short8*)(t + chunk * 512 + l * 8) = v;
        }
    } else if (bid < 2724) {
        const int NQ = 144 * 24 * 64;          // qkv 16B-units
        const int NP = NQ + 48 * 24 * 64;      // + proj 16B-units
        int u = (bid - 1536) * 256 + tid;
        if (u < NP) {
            const float* w = (u < NQ) ? wq : wp;
            int ub = (u < NQ) ? u : u - NQ;
            int chunk = ub >> 6, l = ub & 63;
            int n16 = chunk / 24, kc = chunk - n16 * 24;
            int n = n16 * 16 + (l & 15);
            int k0 = kc * 32 + (l >> 4) * 8;
            const float* src = w + (size_t)n * 768 + k0;
            float4 a = *(const float4*)src;
            float4 b2 = *(const float4*)(src + 4);
            short8 v;
            v[0] = (short)f2bf(a.x);  v[1] = (short)f2bf(a.y);
            v[2] = (short)f2bf(a.z);  v[3] = (short)f2bf(a.w);
            v[4] = (short)f2bf(b2.x); v[5] = (short)f2bf(b2.y);
            v[6] = (short)f2bf(b2.z); v[7] = (short)f2bf(b2.w);
            *(short8*)(wout + (size_t)u * 8) = v;
        } else {
            int i = u - NP;  // 9216 pw elements
            wout[(size_t)NP * 8 + i] = f2bf(wpw[i]);
        }
    } else {
        int i = (bid - 2724) * 256 + tid;  // 28672 floats: sqq|sqk|musum|sqsum
        zbuf[i] = 0.f;
    }
}

// ---------------- GEMM: C(M,N) = A_swiz(M,K) * W_swiz(N,K)^T, bf16 MFMA ----------------
// BK=64, XCD-pinned swizzle. MODE 0 q/k/v epilogue staged through LDS -> 1024B coalesced stores.
// Fused stats: MODE 0 accumulates column sum-of-squares (q,k) into sqa/ska;
// MODE 1 accumulates row sum / sum-of-squares into musum/sqsum; writes Co in bf16
// (staged through LDS [128][136] -> 256B-segment coalesced stores).
template <int MODE>
__global__ __launch_bounds__(256) void gemm_bt(const u16* __restrict__ A,
                                               const u16* __restrict__ Bw,
                                               int M, int N, int K,
                                               u16* __restrict__ qo, u16* __restrict__ ko,
                                               u16* __restrict__ vo,
                                               const float* __restrict__ bias,
                                               u16* __restrict__ Co,
                                               float* __restrict__ sqa,
                                               float* __restrict__ ska,
                                               float* __restrict__ musum,
                                               float* __restrict__ sqsum) {
    __shared__ __align__(16) u16 lAB[128 * 136];  // 34.8KB: staging (32KB) + mode-1 padded C tile
    u16* lA = lAB;
    u16* lB = lAB + 16 * 512;
    const int tid = threadIdx.x;
    const int lane = tid & 63;
    const int wv = tid >> 6;
    const int wr = wv >> 1, wc = wv & 1;
    const int ntiles = N >> 7;
    const int mtiles = M >> 7;                 // 64
    const int lin = blockIdx.x;
    const int xcd = lin & 7;
    const int idx = lin >> 3;
    const int mlocal = idx / ntiles;
    const int ntile = idx - mlocal * ntiles;
    const int m0 = (xcd * (mtiles >> 3) + mlocal) << 7;
    const int n0 = ntile << 7;
    const int lr = lane & 15;
    const int lq = lane >> 4;

    floatx4 acc[4][4];
#pragma unroll
    for (int i = 0; i < 4; i++)
#pragma unroll
        for (int j = 0; j < 4; j++) acc[i][j] = (floatx4){0.f, 0.f, 0.f, 0.f};

    const int m16 = m0 >> 4, n16 = n0 >> 4;
    for (int kc2 = 0; kc2 < (K >> 6); kc2++) {
        __syncthreads();
#pragma unroll
        for (int kh = 0; kh < 2; kh++) {
#pragma unroll
            for (int i = 0; i < 2; i++) {
                int ch16 = i * 4 + wv;       // 16-row block of the 128-row tile
                int kc = kc2 * 2 + kh;
                const u16* ga = A + ((size_t)(m16 + ch16) * 24 + kc) * 512 + lane * 8;
                gl_lds16(ga, (char*)lA + (kh * 8 + ch16) * 1024);
                const u16* gb = Bw + ((size_t)(n16 + ch16) * 24 + kc) * 512 + lane * 8;
                gl_lds16(gb, (char*)lB + (kh * 8 + ch16) * 1024);
            }
        }
        __syncthreads();
#pragma unroll
        for (int kh = 0; kh < 2; kh++) {
            short8 af[4], bfr[4];
#pragma unroll
            for (int tt = 0; tt < 4; tt++) {
                af[tt] = *(const short8*)(lA + ((kh * 8 + wr * 4 + tt) * 64 + lane) * 8);
                bfr[tt] = *(const short8*)(lB + ((kh * 8 + wc * 4 + tt) * 64 + lane) * 8);
            }
#pragma unroll
            for (int mt = 0; mt < 4; mt++)
#pragma unroll
                for (int nt = 0; nt < 4; nt++)
                    acc[mt][nt] = __builtin_amdgcn_mfma_f32_16x16x32_bf16(af[mt], bfr[nt], acc[mt][nt], 0, 0, 0);
        }
    }

    if (MODE == 0) {
        const int region = n0 / 768;       // whole block is q, k, or v
        const int n0r = n0 - region * 768;
        const int bb0 = m0 >> 10;
        // fused column sum-of-squares for q (region 0) and k (region 1)
        if (region < 2) {
            float* dst = (region == 0) ? sqa : ska;
#pragma unroll
            for (int nt = 0; nt < 4; nt++) {
                int colb = n0r + wc * 64 + nt * 16;
                int h = colb / 192;
                int dh = colb - h * 192 + lr;
                float s = 0.f;
#pragma unroll
                for (int mt = 0; mt < 4; mt++)
#pragma unroll
                    for (int r = 0; r < 4; r++) s += acc[mt][nt][r] * acc[mt][nt][r];
                s += __shfl_xor(s, 16);
                s += __shfl_xor(s, 32);
                if (lq == 0) atomicAdd(&dst[(bb0 * 4 + h) * 192 + dh], s);
            }
        }
        // q/k/v: stage the 128x128 bf16 tile in LDS at swiz-exact offsets, bulk-copy out.
        // q uses the SAME swiz layout as k (chunk = (n>>4)*6 + (dh>>5)) so attention reads
        // A-fragments with fully-coalesced 1KB wave loads.
        __syncthreads();
        if (region < 2) {
#pragma unroll
            for (int nt = 0; nt < 4; nt++) {
                int lch = wc * 2 + (nt >> 1);
                int offbase = (((nt & 1) * 2 + (lr >> 3)) * 16) * 8 + (lr & 7);
#pragma unroll
                for (int mt = 0; mt < 4; mt++) {
                    u16* cp2 = lAB + (((wr * 4 + mt) * 4 + lch) * 512);
#pragma unroll
                    for (int r = 0; r < 4; r++)
                        cp2[offbase + (lq * 4 + r) * 8] = f2bf(acc[mt][nt][r]);
                }
            }
        } else {
#pragma unroll
            for (int nt = 0; nt < 4; nt++) {
#pragma unroll
                for (int mt = 0; mt < 4; mt++) {
                    u16* cp2 = lAB + (((wr * 2 + (mt >> 1)) * 8 + wc * 4 + nt) * 512);
                    int ob = (((mt & 1) * 2 + (lq >> 1)) * 16 + lr) * 8 + (lq & 1) * 4;
#pragma unroll
                    for (int r = 0; r < 4; r++)
                        cp2[ob + r] = f2bf(acc[mt][nt][r]);
                }
            }
        }
        __syncthreads();
        const int b = m0 >> 10;
        const int ml = m0 & 1023;
        u16* dsto = (region == 0) ? qo : (region == 1) ? ko : vo;
#pragma unroll
        for (int i = 0; i < 8; i++) {
            int ci = wv * 8 + i;
            short8 val = *(const short8*)(lAB + ci * 512 + lane * 8);
            if (region < 2) {
                int a = ci >> 2, bb = ci & 3;
                int cg = n0r + bb * 32;
                int h = cg / 192;
                int dh32 = (cg - h * 192) >> 5;
                size_t gaddr = (size_t)(b * 4 + h) * 196608 +
                               (size_t)((((ml >> 4) + a) * 6 + dh32)) * 512 + lane * 8;
                *(short8*)(dsto + gaddr) = val;
            } else {
                int a = ci >> 3, bb = ci & 7;
                int cg = n0r + bb * 16;
                int h = cg / 192;
                int dh16 = (cg - h * 192) >> 4;
                size_t gaddr = (size_t)(b * 4 + h) * 196608 +
                               (size_t)((((ml >> 5) + a) * 12 + dh16)) * 512 + lane * 8;
                *(short8*)(dsto + gaddr) = val;
            }
        }
    } else {
        float bvv[4];
#pragma unroll
        for (int nt = 0; nt < 4; nt++) bvv[nt] = bias[n0 + wc * 64 + nt * 16 + lr];
        // fused LN row stats first (registers only): sum / sum-of-squares over 128 cols
#pragma unroll
        for (int mt = 0; mt < 4; mt++) {
#pragma unroll
            for (int r = 0; r < 4; r++) {
                float s = 0.f, ss = 0.f;
#pragma unroll
                for (int nt = 0; nt < 4; nt++) {
                    float v = acc[mt][nt][r] + bvv[nt];
                    s += v;
                    ss += v * v;
                }
#pragma unroll
                for (int m = 1; m < 16; m <<= 1) {
                    s += __shfl_xor(s, m);
                    ss += __shfl_xor(ss, m);
                }
                if (lr == 0) {
                    int row = m0 + wr * 64 + mt * 16 + lq * 4 + r;
                    atomicAdd(&musum[row], s);
                    atomicAdd(&sqsum[row], ss);
                }
            }
        }
        // staged Co store: bf16 tile -> LDS [128][136] (pad kills bank aliasing), then
        // coalesced copy-out: each 16-lane group stores one full 256B row segment.
        __syncthreads();
#pragma unroll
        for (int nt = 0; nt < 4; nt++) {
            int coll = wc * 64 + nt * 16 + lr;
#pragma unroll
            for (int mt = 0; mt < 4; mt++) {
#pragma unroll
                for (int r = 0; r < 4; r++) {
                    int rowl = wr * 64 + mt * 16 + lq * 4 + r;
                    lAB[rowl * 136 + coll] = f2bf(acc[mt][nt][r] + bvv[nt]);
                }
            }
        }
        __syncthreads();
#pragma unroll
        for (int i = 0; i < 8; i++) {
            int u = i * 256 + tid;        // 2048 units of 8 u16
            int rowl = u >> 4, l = u & 15;
            short8 val = *(const short8*)(lAB + rowl * 136 + l * 8);
            *(short8*)(Co + (size_t)(m0 + rowl) * N + n0 + l * 8) = val;
        }
    }
}

// ---------------- flash attention: 32-row blocks, 4 waves = (2 row-tiles x 2 k-halves) ----
// Occupancy fix (R5): 1024 blocks, 52KB LDS -> 3 blocks/CU = 12 waves/CU. Each wave computes
// a k-PARTIAL (16 q-rows x its 32 of 64 k-cols); no-max softmax partials merge by plain
// addition of O and l once at the end (in-LDS). Counted-vmcnt pipeline retained unchanged.
__global__ __launch_bounds__(256) void k_attn(const u16* __restrict__ q,
                                              const u16* __restrict__ kmat,
                                              const u16* __restrict__ vT,
                                              const float* __restrict__ sqq,
                                              const float* __restrict__ sqk,
                                              const float* __restrict__ temp,
                                              u16* __restrict__ o) {
    __shared__ __align__(16) u16 lK[24 * 512];   // 24KB K tile; end: O-partial scratch w0/w1
    __shared__ __align__(16) u16 lV[24 * 512];   // 24KB V tile; end: O-partial w2/w3 + o stage
    __shared__ __align__(16) u16 lP[4 * 512];    // per-wave P (16x32); head aliases lcs + l-merge
    float* lcs = (float*)lP;                      // 192 floats, dead before first lp write
    const int lin = blockIdx.x;
    const int qb = (lin >> 3) & 31;              // 32 q-blocks of 32 rows
    const int bh = (lin & 7) * 4 + (lin >> 8);
    const int b = bh >> 2, h = bh & 3;
    const int tid = threadIdx.x;
    const int lane = tid & 63;
    const int wv = tid >> 6;      // 0..3
    const int wrow = wv >> 1;     // row-tile (16 rows)
    const int wcol = wv & 1;      // k-col half (32 of 64)
    const int lr = lane & 15;
    const int lq = lane >> 4;
    const int koff = lq * 8;

    const u16* qbase = q + (size_t)bh * 196608;
    const u16* kbase = kmat + (size_t)bh * 196608;
    const u16* vbase = vT + (size_t)bh * 196608;

    // fused k_scale: cs[dh] = rsqrt(sqq)*rsqrt(sqk)*temperature
    {
        const float tv = temp[bh & 3];
        for (int i = tid; i < 192; i += 256) {
            float rq = 1.f / fmaxf(sqrtf(sqq[bh * 192 + i]), 1e-12f);
            float rk = 1.f / fmaxf(sqrtf(sqk[bh * 192 + i]), 1e-12f);
            lcs[i] = rq * rk * tv;
        }
    }
    __syncthreads();

    // Q fragments for this wave's 16-row tile, read from swiz layout (coalesced), pre-scaled.
    short8 qf[6];
    {
        const int qr16 = qb * 2 + wrow;
#pragma unroll
        for (int ks = 0; ks < 6; ks++) {
            short8 raw = *(const short8*)(qbase + ((size_t)(qr16 * 6 + ks)) * 512 + (size_t)lane * 8);
            short8 sc;
#pragma unroll
            for (int j = 0; j < 8; j++) {
                float f = bf2f((u16)raw[j]) * lcs[ks * 32 + koff + j];
                sc[j] = (short)f2bf(f);
            }
            qf[ks] = sc;
        }
    }

    float l_r[4];
    floatx4 oacc[12];
#pragma unroll
    for (int r = 0; r < 4; r++) l_r[r] = 0.f;
#pragma unroll
    for (int vt = 0; vt < 12; vt++) oacc[vt] = (floatx4){0.f, 0.f, 0.f, 0.f};

    u16* lp = lP + wv * 512;

    // per-wave staging: 6 K chunks / 6 V chunks (4 waves cover 24 each)
    auto stage_K = [&](int kb2) {
#pragma unroll
        for (int i = 0; i < 6; i++) {
            int ch = i * 4 + wv;  // 0..23
            int ks = ch >> 2, nt = ch & 3;
            const u16* gk = kbase + ((size_t)(kb2 * 4 + nt) * 6 + ks) * 512 + lane * 8;
            gl_lds16(gk, (char*)lK + ch * 1024);
        }
    };
    auto stage_V = [&](int kb2) {
#pragma unroll
        for (int i = 0; i < 6; i++) {
            int ch = i * 4 + wv;  // 0..23
            int ks2 = ch / 12, vt2 = ch - ks2 * 12;
            const u16* gv = vbase + ((size_t)(kb2 * 2 + ks2) * 12 + vt2) * 512 + lane * 8;
            gl_lds16(gv, (char*)lV + ch * 1024);
        }
    };

    // prologue: clean vmem counter (Q loads are drained: consumed above), stage K[0]+V[0]
    asm volatile("s_waitcnt vmcnt(0)" ::: "memory");
    stage_K(0);
    stage_V(0);
    asm volatile("s_waitcnt vmcnt(6)" ::: "memory");
    __builtin_amdgcn_s_barrier();

    for (int kb = 0; kb < 16; kb++) {
        // S = Qs * K^T on this wave's 32 k-cols (chunks wcol*2+nt)
        floatx4 s0[2];
#pragma unroll
        for (int nt = 0; nt < 2; nt++) s0[nt] = (floatx4){0.f, 0.f, 0.f, 0.f};
        __builtin_amdgcn_s_setprio(1);
#pragma unroll
        for (int ks = 0; ks < 6; ks++) {
#pragma unroll
            for (int nt = 0; nt < 2; nt++) {
                short8 kf = *(const short8*)(lK + ((ks * 4 + wcol * 2 + nt) * 64 + lane) * 8);
                s0[nt] = __builtin_amdgcn_mfma_f32_16x16x32_bf16(qf[ks], kf, s0[nt], 0, 0, 0);
            }
        }
        __builtin_amdgcn_s_setprio(0);
        __builtin_amdgcn_s_barrier();     // all waves done reading lK -> safe to overwrite
        if (kb < 15) stage_K(kb + 1);     // K latency hides under softmax + PV

        // exp (no max shift) + partial row-sum + P write (16x32 A-frag order)
        float rs0[4] = {0.f, 0.f, 0.f, 0.f};
#pragma unroll
        for (int nt = 0; nt < 2; nt++)
#pragma unroll
            for (int r = 0; r < 4; r++) {
                float p0 = __expf(s0[nt][r]);
                s0[nt][r] = p0;
                rs0[r] += p0;
            }
#pragma unroll
        for (int m = 1; m < 16; m <<= 1)
#pragma unroll
            for (int r = 0; r < 4; r++) rs0[r] += __shfl_xor(rs0[r], m);
#pragma unroll
        for (int r = 0; r < 4; r++) l_r[r] += rs0[r];
#pragma unroll
        for (int nt = 0; nt < 2; nt++) {
            int base2 = (nt * 2 + (lr >> 3)) * 128 + (lr & 7);
#pragma unroll
            for (int r = 0; r < 4; r++)
                lp[base2 + (lq * 4 + r) * 8] = f2bf(s0[nt][r]);
        }

        // wait V[kb] (oldest 6; K[kb+1]'s 6 may remain in flight), all waves
        if (kb < 15) { asm volatile("s_waitcnt vmcnt(6)" ::: "memory"); }
        else         { asm volatile("s_waitcnt vmcnt(0)" ::: "memory"); }
        __builtin_amdgcn_s_barrier();

        // O-partial += P * V over this wave's 32 k-rows (V chunk half = wcol)
        __builtin_amdgcn_s_setprio(1);
        {
            short8 pf0 = *(const short8*)(lp + lane * 8);
#pragma unroll
            for (int vt = 0; vt < 12; vt++) {
                short8 vf = *(const short8*)(lV + ((wcol * 12 + vt) * 64 + lane) * 8);
                oacc[vt] = __builtin_amdgcn_mfma_f32_16x16x32_bf16(pf0, vf, oacc[vt], 0, 0, 0);
            }
        }
        __builtin_amdgcn_s_setprio(0);
        __builtin_amdgcn_s_barrier();     // all waves done reading lV -> safe to overwrite
        if (kb < 15) {
            stage_V(kb + 1);              // V latency hides under next QK^T + softmax
            asm volatile("s_waitcnt vmcnt(6)" ::: "memory");  // K[kb+1] complete
            __builtin_amdgcn_s_barrier();
        }
    }

    // ---- merge k-partials within wave pairs (0,1) and (2,3): O and l add directly ----
    __syncthreads();
    float lfull[4];
    {
        u16* base = (wv < 2) ? lK : lV;
        float* mine = (float*)(base + (wv & 1) * 6144);       // 12KB per wave
#pragma unroll
        for (int vt = 0; vt < 12; vt++)
#pragma unroll
            for (int r = 0; r < 4; r++) mine[(vt * 64 + lane) * 4 + r] = oacc[vt][r];
        if (lr == 0) {
            float* Lw = (float*)lP + wv * 16;
#pragma unroll
            for (int r = 0; r < 4; r++) Lw[lq * 4 + r] = l_r[r];
        }
        __syncthreads();
        const float* theirs = (const float*)(base + ((wv & 1) ^ 1) * 6144);
        const float* Lp = (const float*)lP + (wv ^ 1) * 16;
#pragma unroll
        for (int vt = 0; vt < 12; vt++)
#pragma unroll
            for (int r = 0; r < 4; r++) oacc[vt][r] += theirs[(vt * 64 + lane) * 4 + r];
#pragma unroll
        for (int r = 0; r < 4; r++) lfull[r] = l_r[r] + Lp[lq * 4 + r];
    }
    __syncthreads();

    // epilogue: divide by l; stage o tile (32 rows x 192 cols) in lV[0..12KB) at block-local
    // swiz offsets, then bulk-store with 16B/lane fully-coalesced writes.
    // each wave writes its row-tile x its 6-column-tile half (disjoint).
    {
        float inv[4];
#pragma unroll
        for (int r = 0; r < 4; r++) inv[r] = 1.f / lfull[r];
#pragma unroll
        for (int i = 0; i < 6; i++) {
            int vt = wcol * 6 + i;
            int col = vt * 16 + lr;
            int swb = (col >> 5) * 512 + (((col >> 3) & 3) * 16) * 8 + (col & 7);
#pragma unroll
            for (int r = 0; r < 4; r++) {
                int rowl = wrow * 16 + lq * 4 + r;
                lV[(rowl >> 4) * 3072 + swb + (rowl & 15) * 8] = f2bf(oacc[vt][r] * inv[r]);
            }
        }
    }
    __syncthreads();
#pragma unroll
    for (int i = 0; i < 3; i++) {
        int u = i * 256 + tid;            // 768 units of 16B
        int chl = u >> 6, l2 = u & 63;
        short8 val = *(const short8*)(lV + chl * 512 + l2 * 8);
        int a = chl / 6, kc = chl - a * 6;
        size_t gaddr = ((size_t)(b * 64 + qb * 2 + a) * 24 + h * 6 + kc) * 512 + l2 * 8;
        *(short8*)(o + gaddr) = val;
    }
}

// ---------------- LN apply + transpose back + residual: y = LN(o2)^T + x ----------------
// (mu/rstd computed inline from musum/sqsum; o2 is bf16)
__global__ __launch_bounds__(256) void k_lnt(const u16* __restrict__ o2,
                                             const float* __restrict__ musum,
                                             const float* __restrict__ sqsum,
                                             const float* __restrict__ gamma,
                                             const float* __restrict__ beta,
                                             const float* __restrict__ x,
                                             float* __restrict__ y) {
    __shared__ float tile[64][65];
    const int b = blockIdx.z, hw0 = blockIdx.y * 64, cd0 = blockIdx.x * 64;
    const int tid = threadIdx.x;
#pragma unroll
    for (int i = 0; i < 16; i++) {
        int f = i * 256 + tid;
        int hwl = f >> 6, cdl = f & 63;
        int row = b * 1024 + hw0 + hwl;
        float m_ = musum[row] * (1.f / 768.f);
        float var = fmaxf(sqsum[row] * (1.f / 768.f) - m_ * m_, 0.f);
        float rstd = rsqrtf(var + 1e-5f);
        float v = bf2f(o2[(size_t)row * 768 + cd0 + cdl]);
        v = (v - m_) * rstd * gamma[cd0 + cdl] + beta[cd0 + cdl];
        tile[hwl][cdl] = v;
    }
    __syncthreads();
#pragma unroll
    for (int i = 0; i < 16; i++) {
        int f = i * 256 + tid;
        int cdl = f >> 6, hwl = f & 63;
        int cd = cd0 + cdl, c = cd >> 3, d = cd & 7;
        size_t addr = (size_t)((b * 96 + c) * 8 + d) * 1024 + hw0 + hwl;
        y[addr] = tile[hwl][cdl] + x[addr];
    }
}

// ---------------- depthwise 3x3x3 conv: LDS-staged channel + rolling d-window ----------------
// z written in bf16 (halves z traffic; feeds pw conv whose contribution is small)
__global__ __launch_bounds__(256) void k_dw(const float* __restrict__ y,
                                            const float* __restrict__ w,
                                            const float* __restrict__ bias,
                                            u16* __restrict__ z) {
    __shared__ float ly[8192];  // [d][h][w]
    const int bc = blockIdx.x;
    const int c = bc % 96;
    const int tid = threadIdx.x;
    const size_t base = (size_t)bc * 8192;

#pragma unroll
    for (int i = 0; i < 8; i++) {
        int i4 = i * 256 + tid;
        *(float4*)(ly + i4 * 4) = *(const float4*)(y + base + i4 * 4);
    }
    float wt[27];
#pragma unroll
    for (int j = 0; j < 27; j++) wt[j] = w[c * 27 + j];
    const float bv = bias[c];
    __syncthreads();

    const int wcol = tid & 31;
    const int hh = tid >> 5;  // 0..7

    for (int hb = 0; hb < 4; hb++) {
        const int h = hb * 8 + hh;
        float pl[3][9];
        auto loadplane = [&](int dd, float* p) {
#pragma unroll
            for (int kh = 0; kh < 3; kh++) {
                int h2 = h + kh - 1;
                bool hok = (unsigned)h2 < 32u;
                const float* row = ly + dd * 1024 + h2 * 32;
#pragma unroll
                for (int kw = 0; kw < 3; kw++) {
                    int w2 = wcol + kw - 1;
                    bool ok = hok && (unsigned)w2 < 32u;
                    p[kh * 3 + kw] = ok ? row[w2] : 0.f;
                }
            }
        };
#pragma unroll
        for (int j = 0; j < 9; j++) pl[0][j] = 0.f;  // d=-1 plane
        loadplane(0, pl[1]);
#pragma unroll
        for (int d = 0; d < 8; d++) {
            if (d < 7) loadplane(d + 1, pl[2]);
            else {
#pragma unroll
                for (int j = 0; j < 9; j++) pl[2][j] = 0.f;
            }
            float acc = bv;
#pragma unroll
            for (int kd = 0; kd < 3; kd++)
#pragma unroll
                for (int j = 0; j < 9; j++) acc += wt[kd * 9 + j] * pl[kd][j];
            z[base + d * 1024 + h * 32 + wcol] = f2bf(acc);
#pragma unroll
            for (int j = 0; j < 9; j++) { pl[0][j] = pl[1][j]; pl[1][j] = pl[2][j]; }
        }
    }
}

// ---------------- pointwise conv via MFMA: out = y + pw_b + W(96x96) * Z(96 x pos) ----------------
// z is already bf16: staging is a straight u16 copy
__global__ __launch_bounds__(256) void k_pw(const u16* __restrict__ z,
                                            const u16* __restrict__ wbf,   // bf16 96x96 row-major
                                            const float* __restrict__ bias,
                                            float* __restrict__ out) {
    __shared__ __align__(16) u16 lZ[128 * 104];
    __shared__ __align__(16) u16 lW[96 * 104];
    const int tid = threadIdx.x;
    const int lane = tid & 63;
    const int wv = tid >> 6;
    const int lr = lane & 15;
    const int lq = lane >> 4;
    const int koff = lq * 8;

    const int idx = blockIdx.x;
    const int q = idx & 7;
    const int bd = idx >> 3;
    const int b = bd >> 3, d = bd & 7;
    const int pos0 = q * 128;

    for (int i = tid; i < 96 * 96; i += 256) {
        int row = i / 96, col = i - row * 96;
        lW[row * 104 + col] = wbf[i];
    }
    {
        const int pos = tid & 127;
        const int cc0 = (tid >> 7) * 48;
        const size_t gbase = ((size_t)b * 96 * 8 + d) * 1024 + pos0 + pos;
#pragma unroll
        for (int g = 0; g < 6; g++) {
            short8 v;
#pragma unroll
            for (int j = 0; j < 8; j++) {
                int cc = cc0 + g * 8 + j;
                v[j] = (short)z[gbase + (size_t)cc * 8192];
            }
            *(short8*)(lZ + pos * 104 + cc0 + g * 8) = v;
        }
    }
    __syncthreads();

    floatx4 acc[6][2];
#pragma unroll
    for (int m = 0; m < 6; m++)
#pragma unroll
        for (int nt = 0; nt < 2; nt++) acc[m][nt] = (floatx4){0.f, 0.f, 0.f, 0.f};

#pragma unroll
    for (int ks = 0; ks < 3; ks++) {
        short8 bfrg[2];
#pragma unroll
        for (int nt = 0; nt < 2; nt++)
            bfrg[nt] = *(const short8*)(lZ + (wv * 32 + nt * 16 + lr) * 104 + ks * 32 + koff);
#pragma unroll
        for (int m = 0; m < 6; m++) {
            short8 afr = *(const short8*)(lW + (m * 16 + lr) * 104 + ks * 32 + koff);
#pragma unroll
            for (int nt = 0; nt < 2; nt++)
                acc[m][nt] = __builtin_amdgcn_mfma_f32_16x16x32_bf16(afr, bfrg[nt], acc[m][nt], 0, 0, 0);
        }
    }

#pragma unroll
    for (int m = 0; m < 6; m++) {
#pragma unroll
        for (int r = 0; r < 4; r++) {
            int c = m * 16 + lq * 4 + r;
            float bv = bias[c];
            size_t rowbase = ((size_t)(b * 96 + c) * 8 + d) * 1024 + pos0;
#pragma unroll
            for (int nt = 0; nt < 2; nt++) {
                int pos = wv * 32 + nt * 16 + lr;
                size_t a = rowbase + pos;
                out[a] = out[a] + bv + acc[m][nt][r];
            }
        }
    }
}

extern "C" void kernel_launch(void* const* d_in, const int* in_sizes, int n_in,
                              void* d_out, int out_size, void* d_ws, size_t ws_size,
                              hipStream_t stream) {
    (void)in_sizes; (void)n_in; (void)out_size; (void)ws_size;
    const float* x      = (const float*)d_in[0];
    const float* pos    = (const float*)d_in[1];
    const float* qkv_w  = (const float*)d_in[2];
    const float* proj_w = (const float*)d_in[3];
    const float* proj_b = (const float*)d_in[4];
    const float* temp   = (const float*)d_in[5];
    const float* ln_g   = (const float*)d_in[6];
    const float* ln_b   = (const float*)d_in[7];
    const float* dw_w   = (const float*)d_in[8];
    const float* dw_b   = (const float*)d_in[9];
    const float* pw_w   = (const float*)d_in[10];
    const float* pw_b   = (const float*)d_in[11];
    float* out = (float*)d_out;
    char* ws = (char*)d_ws;

    u16* t    = (u16*)(ws + 0);           // swiz A, 12.58MB ; later aliased by o (swiz) and z
    u16* vT   = (u16*)(ws + 12582912);    // v swiz, 12.58MB
    u16* q    = (u16*)(ws + 25165824);    // q swiz (k-layout), 12.58MB ; later o2 bf16 (aliases q)
    u16* kk   = (u16*)(ws + 37748736);    // k swiz, 12.58MB
    u16* wqb  = (u16*)(ws + 50331648);    // qkv_w swiz + proj_w swiz + pw_w, ~4.74MB
    float* sqq   = (float*)(ws + 55175168);  // sqq|sqk|musum|sqsum contiguous, 114688B
    float* sqk   = (float*)(ws + 55199744);
    float* musum = (float*)(ws + 55224320);
    float* sqsum = (float*)(ws + 55257088);
    u16* wpb  = wqb + 2304 * 768;
    u16* wpwb = wqb + 2304 * 768 + 768 * 768;
    u16* o   = t;
    u16* o2  = q;       // proj output bf16, aliases q (dead after attention)
    u16* z   = t;       // depthwise output bf16, aliases t (dead after proj GEMM)
    float* y  = out;

    k_init<<<2836, 256, 0, stream>>>(x, pos, qkv_w, proj_w, pw_w, t, wqb, sqq);
    gemm_bt<0><<<1152, 256, 0, stream>>>(t, wqb, 8192, 2304, 768, q, kk, vT, nullptr, nullptr,
                                         sqq, sqk, nullptr, nullptr);
    k_attn<<<1024, 256, 0, stream>>>(q, kk, vT, sqq, sqk, temp, o);
    gemm_bt<1><<<384, 256, 0, stream>>>(o, wpb, 8192, 768, 768, nullptr, nullptr, nullptr, proj_b,
                                        o2, nullptr, nullptr, musum, sqsum);
    k_lnt<<<dim3(12, 16, 8), 256, 0, stream>>>(o2, musum, sqsum, ln_g, ln_b, x, y);
    k_dw<<<768, 256, 0, stream>>>(y, dw_w, dw_b, z);
    k_pw<<<512, 256, 0, stream>>>(z, wpwb, pw_b, out);
}

// Round 10
// 253.850 us; speedup vs baseline: 1.1340x; 1.1340x over previous
//
#include <hip/hip_runtime.h>

typedef unsigned short u16;
typedef unsigned int u32;

typedef __attribute__((ext_vector_type(8))) short short8;
typedef __attribute__((ext_vector_type(4))) float floatx4;

__device__ __forceinline__ float bf2f(u16 u) { return __uint_as_float(((u32)u) << 16); }
__device__ __forceinline__ u16 f2bf(float f) {
    u32 x = __float_as_uint(f);
    x += 0x7fffu + ((x >> 16) & 1u);
    return (u16)(x >> 16);
}
__device__ __forceinline__ void gl_lds16(const void* g, void* l) {
    __builtin_amdgcn_global_load_lds((const __attribute__((address_space(1))) u32*)g,
                                     (__attribute__((address_space(3))) u32*)l, 16, 0, 0);
}

// Fragment-tiled ("swiz") layouts: data grouped in 1024B chunks of [16 rows x 32 k],
// element order = gl_lds16 lane order: u16 off = chunk*512 + (((k>>3)&3)*16 + (row&15))*8 + (k&7).
// A-operands (t, o): chunk = (row>>4)*24 + (k>>5)   [K=768 -> 24 kchunks]
// W-operands (qkv_w, proj_w): same with row=n.
// Q/K-swiz (per bh, n x dh): chunk = (n>>4)*6 + (dh>>5)
// V-swiz (per bh): chunk = (n>>5)*12 + (dh>>4), lane = ((n>>3)&3)*16 + (dh&15), low3 = n&7

// ---------------- fused startup: tpos-transpose | weight cvt | stats zeroing ----------------
// blocks [0,1536): x -> t swiz bf16 + pos ; [1536,2724): weight cvt ; [2724,2836): zero stats
__global__ __launch_bounds__(256) void k_init(const float* __restrict__ x,
                                              const float* __restrict__ pos,
                                              const float* __restrict__ wq,
                                              const float* __restrict__ wp,
                                              const float* __restrict__ wpw,
                                              u16* __restrict__ t,
                                              u16* __restrict__ wout,
                                              float* __restrict__ zbuf) {
    __shared__ float tile[64][65];
    const int bid = blockIdx.x;
    const int tid = threadIdx.x;
    if (bid < 1536) {
        const int cd0 = (bid % 12) * 64;
        const int hw0 = ((bid / 12) & 15) * 64;
        const int b = bid / 192;
#pragma unroll
        for (int i = 0; i < 16; i++) {
            int f = i * 256 + tid;
            int cdl = f >> 6, hwl = f & 63;
            int cd = cd0 + cdl, c = cd >> 3, d = cd & 7;
            tile[cdl][hwl] = x[(size_t)(((b * 96 + c) * 8 + d)) * 1024 + hw0 + hwl];
        }
        __syncthreads();
#pragma unroll
        for (int it = 0; it < 2; it++) {
            int u = it * 256 + tid;       // 512 units of 16B
            int ch = u >> 6, l = u & 63;
            int n16l = ch >> 1, kcl = ch & 1;
            int hwl = n16l * 16 + (l & 15);
            int cdl = kcl * 32 + (l >> 4) * 8;
            int row = b * 1024 + hw0 + hwl;
            int cd = cd0 + cdl;
            const float* pp = pos + (size_t)(hw0 + hwl) * 768 + cd;
            float4 p0 = *(const float4*)pp;
            float4 p1 = *(const float4*)(pp + 4);
            short8 v;
            v[0] = (short)f2bf(tile[cdl + 0][hwl] + p0.x);
            v[1] = (short)f2bf(tile[cdl + 1][hwl] + p0.y);
            v[2] = (short)f2bf(tile[cdl + 2][hwl] + p0.z);
            v[3] = (short)f2bf(tile[cdl + 3][hwl] + p0.w);
            v[4] = (short)f2bf(tile[cdl + 4][hwl] + p1.x);
            v[5] = (short)f2bf(tile[cdl + 5][hwl] + p1.y);
            v[6] = (short)f2bf(tile[cdl + 6][hwl] + p1.z);
            v[7] = (short)f2bf(tile[cdl + 7][hwl] + p1.w);
            size_t chunk = (size_t)(row >> 4) * 24 + (cd >> 5);
            *(short8*)(t + chunk * 512 + l * 8) = v;
        }
    } else if (bid < 2724) {
        const int NQ = 144 * 24 * 64;          // qkv 16B-units
        const int NP = NQ + 48 * 24 * 64;      // + proj 16B-units
        int u = (bid - 1536) * 256 + tid;
        if (u < NP) {
            const float* w = (u < NQ) ? wq : wp;
            int ub = (u < NQ) ? u : u - NQ;
            int chunk = ub >> 6, l = ub & 63;
            int n16 = chunk / 24, kc = chunk - n16 * 24;
            int n = n16 * 16 + (l & 15);
            int k0 = kc * 32 + (l >> 4) * 8;
            const float* src = w + (size_t)n * 768 + k0;
            float4 a = *(const float4*)src;
            float4 b2 = *(const float4*)(src + 4);
            short8 v;
            v[0] = (short)f2bf(a.x);  v[1] = (short)f2bf(a.y);
            v[2] = (short)f2bf(a.z);  v[3] = (short)f2bf(a.w);
            v[4] = (short)f2bf(b2.x); v[5] = (short)f2bf(b2.y);
            v[6] = (short)f2bf(b2.z); v[7] = (short)f2bf(b2.w);
            *(short8*)(wout + (size_t)u * 8) = v;
        } else {
            int i = u - NP;  // 9216 pw elements
            wout[(size_t)NP * 8 + i] = f2bf(wpw[i]);
        }
    } else {
        int i = (bid - 2724) * 256 + tid;  // 28672 floats: sqq|sqk|musum|sqsum
        zbuf[i] = 0.f;
    }
}

// ---------------- GEMM: C(M,N) = A_swiz(M,K) * W_swiz(N,K)^T, bf16 MFMA ----------------
// BK=64, XCD-pinned swizzle. MODE 0 q/k/v epilogue staged through LDS -> 1024B coalesced stores.
// Fused stats: MODE 0 accumulates column sum-of-squares (q,k) into sqa/ska;
// MODE 1 accumulates row sum / sum-of-squares into musum/sqsum; writes Co in bf16
// (staged through LDS [128][136] -> 256B-segment coalesced stores).
template <int MODE>
__global__ __launch_bounds__(256) void gemm_bt(const u16* __restrict__ A,
                                               const u16* __restrict__ Bw,
                                               int M, int N, int K,
                                               u16* __restrict__ qo, u16* __restrict__ ko,
                                               u16* __restrict__ vo,
                                               const float* __restrict__ bias,
                                               u16* __restrict__ Co,
                                               float* __restrict__ sqa,
                                               float* __restrict__ ska,
                                               float* __restrict__ musum,
                                               float* __restrict__ sqsum) {
    __shared__ __align__(16) u16 lAB[128 * 136];  // 34.8KB: staging (32KB) + mode-1 padded C tile
    u16* lA = lAB;
    u16* lB = lAB + 16 * 512;
    const int tid = threadIdx.x;
    const int lane = tid & 63;
    const int wv = tid >> 6;
    const int wr = wv >> 1, wc = wv & 1;
    const int ntiles = N >> 7;
    const int mtiles = M >> 7;                 // 64
    const int lin = blockIdx.x;
    const int xcd = lin & 7;
    const int idx = lin >> 3;
    const int mlocal = idx / ntiles;
    const int ntile = idx - mlocal * ntiles;
    const int m0 = (xcd * (mtiles >> 3) + mlocal) << 7;
    const int n0 = ntile << 7;
    const int lr = lane & 15;
    const int lq = lane >> 4;

    floatx4 acc[4][4];
#pragma unroll
    for (int i = 0; i < 4; i++)
#pragma unroll
        for (int j = 0; j < 4; j++) acc[i][j] = (floatx4){0.f, 0.f, 0.f, 0.f};

    const int m16 = m0 >> 4, n16 = n0 >> 4;
    for (int kc2 = 0; kc2 < (K >> 6); kc2++) {
        __syncthreads();
#pragma unroll
        for (int kh = 0; kh < 2; kh++) {
#pragma unroll
            for (int i = 0; i < 2; i++) {
                int ch16 = i * 4 + wv;       // 16-row block of the 128-row tile
                int kc = kc2 * 2 + kh;
                const u16* ga = A + ((size_t)(m16 + ch16) * 24 + kc) * 512 + lane * 8;
                gl_lds16(ga, (char*)lA + (kh * 8 + ch16) * 1024);
                const u16* gb = Bw + ((size_t)(n16 + ch16) * 24 + kc) * 512 + lane * 8;
                gl_lds16(gb, (char*)lB + (kh * 8 + ch16) * 1024);
            }
        }
        __syncthreads();
#pragma unroll
        for (int kh = 0; kh < 2; kh++) {
            short8 af[4], bfr[4];
#pragma unroll
            for (int tt = 0; tt < 4; tt++) {
                af[tt] = *(const short8*)(lA + ((kh * 8 + wr * 4 + tt) * 64 + lane) * 8);
                bfr[tt] = *(const short8*)(lB + ((kh * 8 + wc * 4 + tt) * 64 + lane) * 8);
            }
#pragma unroll
            for (int mt = 0; mt < 4; mt++)
#pragma unroll
                for (int nt = 0; nt < 4; nt++)
                    acc[mt][nt] = __builtin_amdgcn_mfma_f32_16x16x32_bf16(af[mt], bfr[nt], acc[mt][nt], 0, 0, 0);
        }
    }

    if (MODE == 0) {
        const int region = n0 / 768;       // whole block is q, k, or v
        const int n0r = n0 - region * 768;
        const int bb0 = m0 >> 10;
        // fused column sum-of-squares for q (region 0) and k (region 1)
        if (region < 2) {
            float* dst = (region == 0) ? sqa : ska;
#pragma unroll
            for (int nt = 0; nt < 4; nt++) {
                int colb = n0r + wc * 64 + nt * 16;
                int h = colb / 192;
                int dh = colb - h * 192 + lr;
                float s = 0.f;
#pragma unroll
                for (int mt = 0; mt < 4; mt++)
#pragma unroll
                    for (int r = 0; r < 4; r++) s += acc[mt][nt][r] * acc[mt][nt][r];
                s += __shfl_xor(s, 16);
                s += __shfl_xor(s, 32);
                if (lq == 0) atomicAdd(&dst[(bb0 * 4 + h) * 192 + dh], s);
            }
        }
        // q/k/v: stage the 128x128 bf16 tile in LDS at swiz-exact offsets, bulk-copy out.
        // q uses the SAME swiz layout as k (chunk = (n>>4)*6 + (dh>>5)) so attention reads
        // A-fragments with fully-coalesced 1KB wave loads.
        __syncthreads();
        if (region < 2) {
#pragma unroll
            for (int nt = 0; nt < 4; nt++) {
                int lch = wc * 2 + (nt >> 1);
                int offbase = (((nt & 1) * 2 + (lr >> 3)) * 16) * 8 + (lr & 7);
#pragma unroll
                for (int mt = 0; mt < 4; mt++) {
                    u16* cp2 = lAB + (((wr * 4 + mt) * 4 + lch) * 512);
#pragma unroll
                    for (int r = 0; r < 4; r++)
                        cp2[offbase + (lq * 4 + r) * 8] = f2bf(acc[mt][nt][r]);
                }
            }
        } else {
#pragma unroll
            for (int nt = 0; nt < 4; nt++) {
#pragma unroll
                for (int mt = 0; mt < 4; mt++) {
                    u16* cp2 = lAB + (((wr * 2 + (mt >> 1)) * 8 + wc * 4 + nt) * 512);
                    int ob = (((mt & 1) * 2 + (lq >> 1)) * 16 + lr) * 8 + (lq & 1) * 4;
#pragma unroll
                    for (int r = 0; r < 4; r++)
                        cp2[ob + r] = f2bf(acc[mt][nt][r]);
                }
            }
        }
        __syncthreads();
        const int b = m0 >> 10;
        const int ml = m0 & 1023;
        u16* dsto = (region == 0) ? qo : (region == 1) ? ko : vo;
#pragma unroll
        for (int i = 0; i < 8; i++) {
            int ci = wv * 8 + i;
            short8 val = *(const short8*)(lAB + ci * 512 + lane * 8);
            if (region < 2) {
                int a = ci >> 2, bb = ci & 3;
                int cg = n0r + bb * 32;
                int h = cg / 192;
                int dh32 = (cg - h * 192) >> 5;
                size_t gaddr = (size_t)(b * 4 + h) * 196608 +
                               (size_t)((((ml >> 4) + a) * 6 + dh32)) * 512 + lane * 8;
                *(short8*)(dsto + gaddr) = val;
            } else {
                int a = ci >> 3, bb = ci & 7;
                int cg = n0r + bb * 16;
                int h = cg / 192;
                int dh16 = (cg - h * 192) >> 4;
                size_t gaddr = (size_t)(b * 4 + h) * 196608 +
                               (size_t)((((ml >> 5) + a) * 12 + dh16)) * 512 + lane * 8;
                *(short8*)(dsto + gaddr) = val;
            }
        }
    } else {
        float bvv[4];
#pragma unroll
        for (int nt = 0; nt < 4; nt++) bvv[nt] = bias[n0 + wc * 64 + nt * 16 + lr];
        // fused LN row stats first (registers only): sum / sum-of-squares over 128 cols
#pragma unroll
        for (int mt = 0; mt < 4; mt++) {
#pragma unroll
            for (int r = 0; r < 4; r++) {
                float s = 0.f, ss = 0.f;
#pragma unroll
                for (int nt = 0; nt < 4; nt++) {
                    float v = acc[mt][nt][r] + bvv[nt];
                    s += v;
                    ss += v * v;
                }
#pragma unroll
                for (int m = 1; m < 16; m <<= 1) {
                    s += __shfl_xor(s, m);
                    ss += __shfl_xor(ss, m);
                }
                if (lr == 0) {
                    int row = m0 + wr * 64 + mt * 16 + lq * 4 + r;
                    atomicAdd(&musum[row], s);
                    atomicAdd(&sqsum[row], ss);
                }
            }
        }
        // staged Co store: bf16 tile -> LDS [128][136] (pad kills bank aliasing), then
        // coalesced copy-out: each 16-lane group stores one full 256B row segment.
        __syncthreads();
#pragma unroll
        for (int nt = 0; nt < 4; nt++) {
            int coll = wc * 64 + nt * 16 + lr;
#pragma unroll
            for (int mt = 0; mt < 4; mt++) {
#pragma unroll
                for (int r = 0; r < 4; r++) {
                    int rowl = wr * 64 + mt * 16 + lq * 4 + r;
                    lAB[rowl * 136 + coll] = f2bf(acc[mt][nt][r] + bvv[nt]);
                }
            }
        }
        __syncthreads();
#pragma unroll
        for (int i = 0; i < 8; i++) {
            int u = i * 256 + tid;        // 2048 units of 8 u16
            int rowl = u >> 4, l = u & 15;
            short8 val = *(const short8*)(lAB + rowl * 136 + l * 8);
            *(short8*)(Co + (size_t)(m0 + rowl) * N + n0 + l * 8) = val;
        }
    }
}

// ---------------- flash attention: 4-wave blocks, 16 q-rows/wave, no-max softmax ----
// R5-verified best (52.6us): 512 blocks, 64-row block, 58KB LDS -> 2 blocks/CU = 8 waves/CU.
// Counted-vmcnt pipeline: K[kb+1] issues after QK^T releases lK; V[kb+1] after PV releases lV.
__global__ __launch_bounds__(256) void k_attn(const u16* __restrict__ q,
                                              const u16* __restrict__ kmat,
                                              const u16* __restrict__ vT,
                                              const float* __restrict__ sqq,
                                              const float* __restrict__ sqk,
                                              const float* __restrict__ temp,
                                              u16* __restrict__ o) {
    __shared__ __align__(16) u16 lK[24 * 512];
    __shared__ __align__(16) u16 lV[24 * 512];
    __shared__ __align__(16) u16 lP[4 * 1024];  // per-wave 1 P-tile (16 rows x 64 k)
    __shared__ float lcs[192];
    const int lin = blockIdx.x;
    const int qb = (lin >> 3) & 15;
    const int bh = (lin & 7) * 4 + (lin >> 7);
    const int b = bh >> 2, h = bh & 3;
    const int tid = threadIdx.x;
    const int lane = tid & 63;
    const int wv = tid >> 6;   // 0..3
    const int lr = lane & 15;
    const int lq = lane >> 4;
    const int koff = lq * 8;

    const u16* qbase = q + (size_t)bh * 196608;
    const u16* kbase = kmat + (size_t)bh * 196608;
    const u16* vbase = vT + (size_t)bh * 196608;

    // fused k_scale: cs[dh] = rsqrt(sqq)*rsqrt(sqk)*temperature
    {
        const float tv = temp[bh & 3];
        for (int i = tid; i < 192; i += 256) {
            float rq = 1.f / fmaxf(sqrtf(sqq[bh * 192 + i]), 1e-12f);
            float rk = 1.f / fmaxf(sqrtf(sqk[bh * 192 + i]), 1e-12f);
            lcs[i] = rq * rk * tv;
        }
    }
    __syncthreads();

    // Q fragments for this wave's 16-row tile, read from swiz layout (coalesced), pre-scaled.
    // swiz read: lane holds row = lane&15, k = ks*32 + (lane>>4)*8 + j  -> scale = lcs[ks*32+koff+j]
    short8 qf[6];
    {
        const int qr16 = qb * 4 + wv;
#pragma unroll
        for (int ks = 0; ks < 6; ks++) {
            short8 raw = *(const short8*)(qbase + ((size_t)(qr16 * 6 + ks)) * 512 + (size_t)lane * 8);
            short8 sc;
#pragma unroll
            for (int j = 0; j < 8; j++) {
                float f = bf2f((u16)raw[j]) * lcs[ks * 32 + koff + j];
                sc[j] = (short)f2bf(f);
            }
            qf[ks] = sc;
        }
    }

    float l_r[4];
    floatx4 oacc[12];
#pragma unroll
    for (int r = 0; r < 4; r++) l_r[r] = 0.f;
#pragma unroll
    for (int vt = 0; vt < 12; vt++) oacc[vt] = (floatx4){0.f, 0.f, 0.f, 0.f};

    u16* lp = lP + wv * 1024;

    // per-wave staging: 6 K chunks / 6 V chunks (4 waves cover 24 each)
    auto stage_K = [&](int kb2) {
#pragma unroll
        for (int i = 0; i < 6; i++) {
            int ch = i * 4 + wv;  // 0..23
            int ks = ch >> 2, nt = ch & 3;
            const u16* gk = kbase + ((size_t)(kb2 * 4 + nt) * 6 + ks) * 512 + lane * 8;
            gl_lds16(gk, (char*)lK + ch * 1024);
        }
    };
    auto stage_V = [&](int kb2) {
#pragma unroll
        for (int i = 0; i < 6; i++) {
            int ch = i * 4 + wv;  // 0..23
            int ks2 = ch / 12, vt2 = ch - ks2 * 12;
            const u16* gv = vbase + ((size_t)(kb2 * 2 + ks2) * 12 + vt2) * 512 + lane * 8;
            gl_lds16(gv, (char*)lV + ch * 1024);
        }
    };

    // prologue: clean vmem counter, then stage K[0]+V[0]; wait K[0] (V[0] stays in flight)
    asm volatile("s_waitcnt vmcnt(0)" ::: "memory");
    stage_K(0);
    stage_V(0);
    asm volatile("s_waitcnt vmcnt(6)" ::: "memory");
    __builtin_amdgcn_s_barrier();

    for (int kb = 0; kb < 16; kb++) {
        // S = Qs * K^T (lK holds K[kb]; this wave's 6 V[kb] loads still outstanding)
        floatx4 s0[4];
#pragma unroll
        for (int nt = 0; nt < 4; nt++) s0[nt] = (floatx4){0.f, 0.f, 0.f, 0.f};
        __builtin_amdgcn_s_setprio(1);
#pragma unroll
        for (int ks = 0; ks < 6; ks++) {
#pragma unroll
            for (int nt = 0; nt < 4; nt++) {
                short8 kf = *(const short8*)(lK + ((ks * 4 + nt) * 64 + lane) * 8);
                s0[nt] = __builtin_amdgcn_mfma_f32_16x16x32_bf16(qf[ks], kf, s0[nt], 0, 0, 0);
            }
        }
        __builtin_amdgcn_s_setprio(0);
        __builtin_amdgcn_s_barrier();     // all waves done reading lK -> safe to overwrite
        if (kb < 15) stage_K(kb + 1);     // K latency hides under softmax + PV

        // exp (no max shift) + row-sum + P write (A-frag order)
        float rs0[4] = {0.f, 0.f, 0.f, 0.f};
#pragma unroll
        for (int nt = 0; nt < 4; nt++)
#pragma unroll
            for (int r = 0; r < 4; r++) {
                float p0 = __expf(s0[nt][r]);
                s0[nt][r] = p0;
                rs0[r] += p0;
            }
#pragma unroll
        for (int m = 1; m < 16; m <<= 1)
#pragma unroll
            for (int r = 0; r < 4; r++) rs0[r] += __shfl_xor(rs0[r], m);
#pragma unroll
        for (int r = 0; r < 4; r++) l_r[r] += rs0[r];
#pragma unroll
        for (int nt = 0; nt < 4; nt++) {
            int base2 = (nt >> 1) * 512 + ((nt & 1) * 2 + (lr >> 3)) * 128 + (lr & 7);
#pragma unroll
            for (int r = 0; r < 4; r++)
                lp[base2 + (lq * 4 + r) * 8] = f2bf(s0[nt][r]);
        }

        // wait V[kb] (oldest 6; K[kb+1]'s 6 may remain in flight), all waves
        if (kb < 15) { asm volatile("s_waitcnt vmcnt(6)" ::: "memory"); }
        else         { asm volatile("s_waitcnt vmcnt(0)" ::: "memory"); }
        __builtin_amdgcn_s_barrier();

        // O += P * V
        __builtin_amdgcn_s_setprio(1);
#pragma unroll
        for (int ks2 = 0; ks2 < 2; ks2++) {
            short8 pf0 = *(const short8*)(lp + ks2 * 512 + lane * 8);
#pragma unroll
            for (int vt = 0; vt < 12; vt++) {
                short8 vf = *(const short8*)(lV + ((ks2 * 12 + vt) * 64 + lane) * 8);
                oacc[vt] = __builtin_amdgcn_mfma_f32_16x16x32_bf16(pf0, vf, oacc[vt], 0, 0, 0);
            }
        }
        __builtin_amdgcn_s_setprio(0);
        __builtin_amdgcn_s_barrier();     // all waves done reading lV -> safe to overwrite
        if (kb < 15) {
            stage_V(kb + 1);              // V latency hides under next QK^T + softmax
            asm volatile("s_waitcnt vmcnt(6)" ::: "memory");  // K[kb+1] complete
            __builtin_amdgcn_s_barrier();
        }
    }

    // epilogue: divide by l, stage o tile (64 rows x 192 cols) in lK at block-local swiz
    // offsets (== global swiz restricted to block: h*192 ≡ 0 mod 32, h*24 ≡ 0 mod 4),
    // then bulk-store 24KB with 16B/lane fully-coalesced writes.
    __syncthreads();   // all waves done with lK
    {
        float inv[4];
#pragma unroll
        for (int r = 0; r < 4; r++) inv[r] = 1.f / l_r[r];
#pragma unroll
        for (int vt = 0; vt < 12; vt++) {
            int col = vt * 16 + lr;
            int swb = (col >> 5) * 512 + (((col >> 3) & 3) * 16) * 8 + (col & 7);
#pragma unroll
            for (int r = 0; r < 4; r++) {
                int rowl = wv * 16 + lq * 4 + r;
                lK[(rowl >> 4) * 3072 + swb + (rowl & 15) * 8] = f2bf(oacc[vt][r] * inv[r]);
            }
        }
    }
    __syncthreads();
#pragma unroll
    for (int i = 0; i < 6; i++) {
        int u = i * 256 + tid;            // 1536 units of 16B
        int chl = u >> 6, l = u & 63;
        short8 val = *(const short8*)(lK + chl * 512 + l * 8);
        int a = chl / 6, kc = chl - a * 6;
        size_t gaddr = ((size_t)(b * 64 + qb * 4 + a) * 24 + h * 6 + kc) * 512 + l * 8;
        *(short8*)(o + gaddr) = val;
    }
}

// ---------------- LN apply + transpose back + residual: y = LN(o2)^T + x ----------------
// (mu/rstd computed inline from musum/sqsum; o2 is bf16)
__global__ __launch_bounds__(256) void k_lnt(const u16* __restrict__ o2,
                                             const float* __restrict__ musum,
                                             const float* __restrict__ sqsum,
                                             const float* __restrict__ gamma,
                                             const float* __restrict__ beta,
                                             const float* __restrict__ x,
                                             float* __restrict__ y) {
    __shared__ float tile[64][65];
    const int b = blockIdx.z, hw0 = blockIdx.y * 64, cd0 = blockIdx.x * 64;
    const int tid = threadIdx.x;
#pragma unroll
    for (int i = 0; i < 16; i++) {
        int f = i * 256 + tid;
        int hwl = f >> 6, cdl = f & 63;
        int row = b * 1024 + hw0 + hwl;
        float m_ = musum[row] * (1.f / 768.f);
        float var = fmaxf(sqsum[row] * (1.f / 768.f) - m_ * m_, 0.f);
        float rstd = rsqrtf(var + 1e-5f);
        float v = bf2f(o2[(size_t)row * 768 + cd0 + cdl]);
        v = (v - m_) * rstd * gamma[cd0 + cdl] + beta[cd0 + cdl];
        tile[hwl][cdl] = v;
    }
    __syncthreads();
#pragma unroll
    for (int i = 0; i < 16; i++) {
        int f = i * 256 + tid;
        int cdl = f >> 6, hwl = f & 63;
        int cd = cd0 + cdl, c = cd >> 3, d = cd & 7;
        size_t addr = (size_t)((b * 96 + c) * 8 + d) * 1024 + hw0 + hwl;
        y[addr] = tile[hwl][cdl] + x[addr];
    }
}

// ---------------- depthwise 3x3x3 conv: LDS-staged channel + rolling d-window ----------------
// z written in bf16 (halves z traffic; feeds pw conv whose contribution is small)
__global__ __launch_bounds__(256) void k_dw(const float* __restrict__ y,
                                            const float* __restrict__ w,
                                            const float* __restrict__ bias,
                                            u16* __restrict__ z) {
    __shared__ float ly[8192];  // [d][h][w]
    const int bc = blockIdx.x;
    const int c = bc % 96;
    const int tid = threadIdx.x;
    const size_t base = (size_t)bc * 8192;

#pragma unroll
    for (int i = 0; i < 8; i++) {
        int i4 = i * 256 + tid;
        *(float4*)(ly + i4 * 4) = *(const float4*)(y + base + i4 * 4);
    }
    float wt[27];
#pragma unroll
    for (int j = 0; j < 27; j++) wt[j] = w[c * 27 + j];
    const float bv = bias[c];
    __syncthreads();

    const int wcol = tid & 31;
    const int hh = tid >> 5;  // 0..7

    for (int hb = 0; hb < 4; hb++) {
        const int h = hb * 8 + hh;
        float pl[3][9];
        auto loadplane = [&](int dd, float* p) {
#pragma unroll
            for (int kh = 0; kh < 3; kh++) {
                int h2 = h + kh - 1;
                bool hok = (unsigned)h2 < 32u;
                const float* row = ly + dd * 1024 + h2 * 32;
#pragma unroll
                for (int kw = 0; kw < 3; kw++) {
                    int w2 = wcol + kw - 1;
                    bool ok = hok && (unsigned)w2 < 32u;
                    p[kh * 3 + kw] = ok ? row[w2] : 0.f;
                }
            }
        };
#pragma unroll
        for (int j = 0; j < 9; j++) pl[0][j] = 0.f;  // d=-1 plane
        loadplane(0, pl[1]);
#pragma unroll
        for (int d = 0; d < 8; d++) {
            if (d < 7) loadplane(d + 1, pl[2]);
            else {
#pragma unroll
                for (int j = 0; j < 9; j++) pl[2][j] = 0.f;
            }
            float acc = bv;
#pragma unroll
            for (int kd = 0; kd < 3; kd++)
#pragma unroll
                for (int j = 0; j < 9; j++) acc += wt[kd * 9 + j] * pl[kd][j];
            z[base + d * 1024 + h * 32 + wcol] = f2bf(acc);
#pragma unroll
            for (int j = 0; j < 9; j++) { pl[0][j] = pl[1][j]; pl[1][j] = pl[2][j]; }
        }
    }
}

// ---------------- pointwise conv via MFMA: out = y + pw_b + W(96x96) * Z(96 x pos) ----------------
// z is already bf16: staging is a straight u16 copy
__global__ __launch_bounds__(256) void k_pw(const u16* __restrict__ z,
                                            const u16* __restrict__ wbf,   // bf16 96x96 row-major
                                            const float* __restrict__ bias,
                                            float* __restrict__ out) {
    __shared__ __align__(16) u16 lZ[128 * 104];
    __shared__ __align__(16) u16 lW[96 * 104];
    const int tid = threadIdx.x;
    const int lane = tid & 63;
    const int wv = tid >> 6;
    const int lr = lane & 15;
    const int lq = lane >> 4;
    const int koff = lq * 8;

    const int idx = blockIdx.x;
    const int q = idx & 7;
    const int bd = idx >> 3;
    const int b = bd >> 3, d = bd & 7;
    const int pos0 = q * 128;

    for (int i = tid; i < 96 * 96; i += 256) {
        int row = i / 96, col = i - row * 96;
        lW[row * 104 + col] = wbf[i];
    }
    {
        const int pos = tid & 127;
        const int cc0 = (tid >> 7) * 48;
        const size_t gbase = ((size_t)b * 96 * 8 + d) * 1024 + pos0 + pos;
#pragma unroll
        for (int g = 0; g < 6; g++) {
            short8 v;
#pragma unroll
            for (int j = 0; j < 8; j++) {
                int cc = cc0 + g * 8 + j;
                v[j] = (short)z[gbase + (size_t)cc * 8192];
            }
            *(short8*)(lZ + pos * 104 + cc0 + g * 8) = v;
        }
    }
    __syncthreads();

    floatx4 acc[6][2];
#pragma unroll
    for (int m = 0; m < 6; m++)
#pragma unroll
        for (int nt = 0; nt < 2; nt++) acc[m][nt] = (floatx4){0.f, 0.f, 0.f, 0.f};

#pragma unroll
    for (int ks = 0; ks < 3; ks++) {
        short8 bfrg[2];
#pragma unroll
        for (int nt = 0; nt < 2; nt++)
            bfrg[nt] = *(const short8*)(lZ + (wv * 32 + nt * 16 + lr) * 104 + ks * 32 + koff);
#pragma unroll
        for (int m = 0; m < 6; m++) {
            short8 afr = *(const short8*)(lW + (m * 16 + lr) * 104 + ks * 32 + koff);
#pragma unroll
            for (int nt = 0; nt < 2; nt++)
                acc[m][nt] = __builtin_amdgcn_mfma_f32_16x16x32_bf16(afr, bfrg[nt], acc[m][nt], 0, 0, 0);
        }
    }

#pragma unroll
    for (int m = 0; m < 6; m++) {
#pragma unroll
        for (int r = 0; r < 4; r++) {
            int c = m * 16 + lq * 4 + r;
            float bv = bias[c];
            size_t rowbase = ((size_t)(b * 96 + c) * 8 + d) * 1024 + pos0;
#pragma unroll
            for (int nt = 0; nt < 2; nt++) {
                int pos = wv * 32 + nt * 16 + lr;
                size_t a = rowbase + pos;
                out[a] = out[a] + bv + acc[m][nt][r];
            }
        }
    }
}

extern "C" void kernel_launch(void* const* d_in, const int* in_sizes, int n_in,
                              void* d_out, int out_size, void* d_ws, size_t ws_size,
                              hipStream_t stream) {
    (void)in_sizes; (void)n_in; (void)out_size; (void)ws_size;
    const float* x      = (const float*)d_in[0];
    const float* pos    = (const float*)d_in[1];
    const float* qkv_w  = (const float*)d_in[2];
    const float* proj_w = (const float*)d_in[3];
    const float* proj_b = (const float*)d_in[4];
    const float* temp   = (const float*)d_in[5];
    const float* ln_g   = (const float*)d_in[6];
    const float* ln_b   = (const float*)d_in[7];
    const float* dw_w   = (const float*)d_in[8];
    const float* dw_b   = (const float*)d_in[9];
    const float* pw_w   = (const float*)d_in[10];
    const float* pw_b   = (const float*)d_in[11];
    float* out = (float*)d_out;
    char* ws = (char*)d_ws;

    u16* t    = (u16*)(ws + 0);           // swiz A, 12.58MB ; later aliased by o (swiz) and z
    u16* vT   = (u16*)(ws + 12582912);    // v swiz, 12.58MB
    u16* q    = (u16*)(ws + 25165824);    // q swiz (k-layout), 12.58MB ; later o2 bf16 (aliases q)
    u16* kk   = (u16*)(ws + 37748736);    // k swiz, 12.58MB
    u16* wqb  = (u16*)(ws + 50331648);    // qkv_w swiz + proj_w swiz + pw_w, ~4.74MB
    float* sqq   = (float*)(ws + 55175168);  // sqq|sqk|musum|sqsum contiguous, 114688B
    float* sqk   = (float*)(ws + 55199744);
    float* musum = (float*)(ws + 55224320);
    float* sqsum = (float*)(ws + 55257088);
    u16* wpb  = wqb + 2304 * 768;
    u16* wpwb = wqb + 2304 * 768 + 768 * 768;
    u16* o   = t;
    u16* o2  = q;       // proj output bf16, aliases q (dead after attention)
    u16* z   = t;       // depthwise output bf16, aliases t (dead after proj GEMM)
    float* y  = out;

    k_init<<<2836, 256, 0, stream>>>(x, pos, qkv_w, proj_w, pw_w, t, wqb, sqq);
    gemm_bt<0><<<1152, 256, 0, stream>>>(t, wqb, 8192, 2304, 768, q, kk, vT, nullptr, nullptr,
                                         sqq, sqk, nullptr, nullptr);
    k_attn<<<512, 256, 0, stream>>>(q, kk, vT, sqq, sqk, temp, o);
    gemm_bt<1><<<384, 256, 0, stream>>>(o, wpb, 8192, 768, 768, nullptr, nullptr, nullptr, proj_b,
                                        o2, nullptr, nullptr, musum, sqsum);
    k_lnt<<<dim3(12, 16, 8), 256, 0, stream>>>(o2, musum, sqsum, ln_g, ln_b, x, y);
    k_dw<<<768, 256, 0, stream>>>(y, dw_w, dw_b, z);
    k_pw<<<512, 256, 0, stream>>>(z, wpwb, pw_b, out);
}

// Round 18
// 247.553 us; speedup vs baseline: 1.1628x; 1.0254x over previous
//
#include <hip/hip_runtime.h>

typedef unsigned short u16;
typedef unsigned int u32;

typedef __attribute__((ext_vector_type(8))) short short8;
typedef __attribute__((ext_vector_type(4))) float floatx4;

__device__ __forceinline__ float bf2f(u16 u) { return __uint_as_float(((u32)u) << 16); }
__device__ __forceinline__ u16 f2bf(float f) {
    u32 x = __float_as_uint(f);
    x += 0x7fffu + ((x >> 16) & 1u);
    return (u16)(x >> 16);
}
__device__ __forceinline__ void gl_lds16(const void* g, void* l) {
    __builtin_amdgcn_global_load_lds((const __attribute__((address_space(1))) u32*)g,
                                     (__attribute__((address_space(3))) u32*)l, 16, 0, 0);
}

// Fragment-tiled ("swiz") layouts: data grouped in 1024B chunks of [16 rows x 32 k],
// element order = gl_lds16 lane order: u16 off = chunk*512 + (((k>>3)&3)*16 + (row&15))*8 + (k&7).
// A-operands (t, o): chunk = (row>>4)*24 + (k>>5)   [K=768 -> 24 kchunks]
// W-operands (qkv_w, proj_w): same with row=n.
// Q/K-swiz (per bh, n x dh): chunk = (n>>4)*6 + (dh>>5)
// V-swiz (per bh): chunk = (n>>5)*12 + (dh>>4), lane = ((n>>3)&3)*16 + (dh&15), low3 = n&7

// ---------------- fused startup: tpos-transpose | weight cvt | stats zeroing ----------------
// blocks [0,1536): x -> t swiz bf16 + pos ; [1536,2724): weight cvt ; [2724,2836): zero stats
__global__ __launch_bounds__(256) void k_init(const float* __restrict__ x,
                                              const float* __restrict__ pos,
                                              const float* __restrict__ wq,
                                              const float* __restrict__ wp,
                                              const float* __restrict__ wpw,
                                              u16* __restrict__ t,
                                              u16* __restrict__ wout,
                                              float* __restrict__ zbuf) {
    __shared__ float tile[64][65];
    const int bid = blockIdx.x;
    const int tid = threadIdx.x;
    if (bid < 1536) {
        const int cd0 = (bid % 12) * 64;
        const int hw0 = ((bid / 12) & 15) * 64;
        const int b = bid / 192;
#pragma unroll
        for (int i = 0; i < 16; i++) {
            int f = i * 256 + tid;
            int cdl = f >> 6, hwl = f & 63;
            int cd = cd0 + cdl, c = cd >> 3, d = cd & 7;
            tile[cdl][hwl] = x[(size_t)(((b * 96 + c) * 8 + d)) * 1024 + hw0 + hwl];
        }
        __syncthreads();
#pragma unroll
        for (int it = 0; it < 2; it++) {
            int u = it * 256 + tid;       // 512 units of 16B
            int ch = u >> 6, l = u & 63;
            int n16l = ch >> 1, kcl = ch & 1;
            int hwl = n16l * 16 + (l & 15);
            int cdl = kcl * 32 + (l >> 4) * 8;
            int row = b * 1024 + hw0 + hwl;
            int cd = cd0 + cdl;
            const float* pp = pos + (size_t)(hw0 + hwl) * 768 + cd;
            float4 p0 = *(const float4*)pp;
            float4 p1 = *(const float4*)(pp + 4);
            short8 v;
            v[0] = (short)f2bf(tile[cdl + 0][hwl] + p0.x);
            v[1] = (short)f2bf(tile[cdl + 1][hwl] + p0.y);
            v[2] = (short)f2bf(tile[cdl + 2][hwl] + p0.z);
            v[3] = (short)f2bf(tile[cdl + 3][hwl] + p0.w);
            v[4] = (short)f2bf(tile[cdl + 4][hwl] + p1.x);
            v[5] = (short)f2bf(tile[cdl + 5][hwl] + p1.y);
            v[6] = (short)f2bf(tile[cdl + 6][hwl] + p1.z);
            v[7] = (short)f2bf(tile[cdl + 7][hwl] + p1.w);
            size_t chunk = (size_t)(row >> 4) * 24 + (cd >> 5);
            *(short8*)(t + chunk * 512 + l * 8) = v;
        }
    } else if (bid < 2724) {
        const int NQ = 144 * 24 * 64;          // qkv 16B-units
        const int NP = NQ + 48 * 24 * 64;      // + proj 16B-units
        int u = (bid - 1536) * 256 + tid;
        if (u < NP) {
            const float* w = (u < NQ) ? wq : wp;
            int ub = (u < NQ) ? u : u - NQ;
            int chunk = ub >> 6, l = ub & 63;
            int n16 = chunk / 24, kc = chunk - n16 * 24;
            int n = n16 * 16 + (l & 15);
            int k0 = kc * 32 + (l >> 4) * 8;
            const float* src = w + (size_t)n * 768 + k0;
            float4 a = *(const float4*)src;
            float4 b2 = *(const float4*)(src + 4);
            short8 v;
            v[0] = (short)f2bf(a.x);  v[1] = (short)f2bf(a.y);
            v[2] = (short)f2bf(a.z);  v[3] = (short)f2bf(a.w);
            v[4] = (short)f2bf(b2.x); v[5] = (short)f2bf(b2.y);
            v[6] = (short)f2bf(b2.z); v[7] = (short)f2bf(b2.w);
            *(short8*)(wout + (size_t)u * 8) = v;
        } else {
            int i = u - NP;  // 9216 pw elements
            wout[(size_t)NP * 8 + i] = f2bf(wpw[i]);
        }
    } else {
        int i = (bid - 2724) * 256 + tid;  // 28672 floats: sqq|sqk|musum|sqsum
        zbuf[i] = 0.f;
    }
}

// ---------------- GEMM: C(M,N) = A_swiz(M,K) * W_swiz(N,K)^T, bf16 MFMA ----------------
// BK=64, XCD-pinned swizzle. MODE 0 q/k/v epilogue staged through LDS -> 1024B coalesced stores.
// Fused stats: MODE 0 accumulates column sum-of-squares (q,k) into sqa/ska;
// MODE 1 accumulates row sum / sum-of-squares into musum/sqsum; writes Co in bf16
// (staged through LDS [128][136] -> 256B-segment coalesced stores).
template <int MODE>
__global__ __launch_bounds__(256) void gemm_bt(const u16* __restrict__ A,
                                               const u16* __restrict__ Bw,
                                               int M, int N, int K,
                                               u16* __restrict__ qo, u16* __restrict__ ko,
                                               u16* __restrict__ vo,
                                               const float* __restrict__ bias,
                                               u16* __restrict__ Co,
                                               float* __restrict__ sqa,
                                               float* __restrict__ ska,
                                               float* __restrict__ musum,
                                               float* __restrict__ sqsum) {
    __shared__ __align__(16) u16 lAB[128 * 136];  // 34.8KB: staging (32KB) + mode-1 padded C tile
    u16* lA = lAB;
    u16* lB = lAB + 16 * 512;
    const int tid = threadIdx.x;
    const int lane = tid & 63;
    const int wv = tid >> 6;
    const int wr = wv >> 1, wc = wv & 1;
    const int ntiles = N >> 7;
    const int mtiles = M >> 7;                 // 64
    const int lin = blockIdx.x;
    const int xcd = lin & 7;
    const int idx = lin >> 3;
    const int mlocal = idx / ntiles;
    const int ntile = idx - mlocal * ntiles;
    const int m0 = (xcd * (mtiles >> 3) + mlocal) << 7;
    const int n0 = ntile << 7;
    const int lr = lane & 15;
    const int lq = lane >> 4;

    floatx4 acc[4][4];
#pragma unroll
    for (int i = 0; i < 4; i++)
#pragma unroll
        for (int j = 0; j < 4; j++) acc[i][j] = (floatx4){0.f, 0.f, 0.f, 0.f};

    const int m16 = m0 >> 4, n16 = n0 >> 4;
    for (int kc2 = 0; kc2 < (K >> 6); kc2++) {
        __syncthreads();
#pragma unroll
        for (int kh = 0; kh < 2; kh++) {
#pragma unroll
            for (int i = 0; i < 2; i++) {
                int ch16 = i * 4 + wv;       // 16-row block of the 128-row tile
                int kc = kc2 * 2 + kh;
                const u16* ga = A + ((size_t)(m16 + ch16) * 24 + kc) * 512 + lane * 8;
                gl_lds16(ga, (char*)lA + (kh * 8 + ch16) * 1024);
                const u16* gb = Bw + ((size_t)(n16 + ch16) * 24 + kc) * 512 + lane * 8;
                gl_lds16(gb, (char*)lB + (kh * 8 + ch16) * 1024);
            }
        }
        __syncthreads();
#pragma unroll
        for (int kh = 0; kh < 2; kh++) {
            short8 af[4], bfr[4];
#pragma unroll
            for (int tt = 0; tt < 4; tt++) {
                af[tt] = *(const short8*)(lA + ((kh * 8 + wr * 4 + tt) * 64 + lane) * 8);
                bfr[tt] = *(const short8*)(lB + ((kh * 8 + wc * 4 + tt) * 64 + lane) * 8);
            }
#pragma unroll
            for (int mt = 0; mt < 4; mt++)
#pragma unroll
                for (int nt = 0; nt < 4; nt++)
                    acc[mt][nt] = __builtin_amdgcn_mfma_f32_16x16x32_bf16(af[mt], bfr[nt], acc[mt][nt], 0, 0, 0);
        }
    }

    if (MODE == 0) {
        const int region = n0 / 768;       // whole block is q, k, or v
        const int n0r = n0 - region * 768;
        const int bb0 = m0 >> 10;
        // fused column sum-of-squares for q (region 0) and k (region 1)
        if (region < 2) {
            float* dst = (region == 0) ? sqa : ska;
#pragma unroll
            for (int nt = 0; nt < 4; nt++) {
                int colb = n0r + wc * 64 + nt * 16;
                int h = colb / 192;
                int dh = colb - h * 192 + lr;
                float s = 0.f;
#pragma unroll
                for (int mt = 0; mt < 4; mt++)
#pragma unroll
                    for (int r = 0; r < 4; r++) s += acc[mt][nt][r] * acc[mt][nt][r];
                s += __shfl_xor(s, 16);
                s += __shfl_xor(s, 32);
                if (lq == 0) atomicAdd(&dst[(bb0 * 4 + h) * 192 + dh], s);
            }
        }
        // q/k/v: stage the 128x128 bf16 tile in LDS at swiz-exact offsets, bulk-copy out.
        // q uses the SAME swiz layout as k (chunk = (n>>4)*6 + (dh>>5)) so attention reads
        // A-fragments with fully-coalesced 1KB wave loads.
        __syncthreads();
        if (region < 2) {
#pragma unroll
            for (int nt = 0; nt < 4; nt++) {
                int lch = wc * 2 + (nt >> 1);
                int offbase = (((nt & 1) * 2 + (lr >> 3)) * 16) * 8 + (lr & 7);
#pragma unroll
                for (int mt = 0; mt < 4; mt++) {
                    u16* cp2 = lAB + (((wr * 4 + mt) * 4 + lch) * 512);
#pragma unroll
                    for (int r = 0; r < 4; r++)
                        cp2[offbase + (lq * 4 + r) * 8] = f2bf(acc[mt][nt][r]);
                }
            }
        } else {
#pragma unroll
            for (int nt = 0; nt < 4; nt++) {
#pragma unroll
                for (int mt = 0; mt < 4; mt++) {
                    u16* cp2 = lAB + (((wr * 2 + (mt >> 1)) * 8 + wc * 4 + nt) * 512);
                    int ob = (((mt & 1) * 2 + (lq >> 1)) * 16 + lr) * 8 + (lq & 1) * 4;
#pragma unroll
                    for (int r = 0; r < 4; r++)
                        cp2[ob + r] = f2bf(acc[mt][nt][r]);
                }
            }
        }
        __syncthreads();
        const int b = m0 >> 10;
        const int ml = m0 & 1023;
        u16* dsto = (region == 0) ? qo : (region == 1) ? ko : vo;
#pragma unroll
        for (int i = 0; i < 8; i++) {
            int ci = wv * 8 + i;
            short8 val = *(const short8*)(lAB + ci * 512 + lane * 8);
            if (region < 2) {
                int a = ci >> 2, bb = ci & 3;
                int cg = n0r + bb * 32;
                int h = cg / 192;
                int dh32 = (cg - h * 192) >> 5;
                size_t gaddr = (size_t)(b * 4 + h) * 196608 +
                               (size_t)((((ml >> 4) + a) * 6 + dh32)) * 512 + lane * 8;
                *(short8*)(dsto + gaddr) = val;
            } else {
                int a = ci >> 3, bb = ci & 7;
                int cg = n0r + bb * 16;
                int h = cg / 192;
                int dh16 = (cg - h * 192) >> 4;
                size_t gaddr = (size_t)(b * 4 + h) * 196608 +
                               (size_t)((((ml >> 5) + a) * 12 + dh16)) * 512 + lane * 8;
                *(short8*)(dsto + gaddr) = val;
            }
        }
    } else {
        float bvv[4];
#pragma unroll
        for (int nt = 0; nt < 4; nt++) bvv[nt] = bias[n0 + wc * 64 + nt * 16 + lr];
        // fused LN row stats first (registers only): sum / sum-of-squares over 128 cols
#pragma unroll
        for (int mt = 0; mt < 4; mt++) {
#pragma unroll
            for (int r = 0; r < 4; r++) {
                float s = 0.f, ss = 0.f;
#pragma unroll
                for (int nt = 0; nt < 4; nt++) {
                    float v = acc[mt][nt][r] + bvv[nt];
                    s += v;
                    ss += v * v;
                }
#pragma unroll
                for (int m = 1; m < 16; m <<= 1) {
                    s += __shfl_xor(s, m);
                    ss += __shfl_xor(ss, m);
                }
                if (lr == 0) {
                    int row = m0 + wr * 64 + mt * 16 + lq * 4 + r;
                    atomicAdd(&musum[row], s);
                    atomicAdd(&sqsum[row], ss);
                }
            }
        }
        // staged Co store: bf16 tile -> LDS [128][136] (pad kills bank aliasing), then
        // coalesced copy-out: each 16-lane group stores one full 256B row segment.
        __syncthreads();
#pragma unroll
        for (int nt = 0; nt < 4; nt++) {
            int coll = wc * 64 + nt * 16 + lr;
#pragma unroll
            for (int mt = 0; mt < 4; mt++) {
#pragma unroll
                for (int r = 0; r < 4; r++) {
                    int rowl = wr * 64 + mt * 16 + lq * 4 + r;
                    lAB[rowl * 136 + coll] = f2bf(acc[mt][nt][r] + bvv[nt]);
                }
            }
        }
        __syncthreads();
#pragma unroll
        for (int i = 0; i < 8; i++) {
            int u = i * 256 + tid;        // 2048 units of 8 u16
            int rowl = u >> 4, l = u & 15;
            short8 val = *(const short8*)(lAB + rowl * 136 + l * 8);
            *(short8*)(Co + (size_t)(m0 + rowl) * N + n0 + l * 8) = val;
        }
    }
}

// ---------------- flash attention: 4-wave blocks, LDS-traffic-minimized partition ----
// R11: the R5 kernel was LDS-read-BW bound (~70% pipe busy: 50 b128 reads/wave/kb).
// Re-partition at same occupancy (512 blocks, 2/CU, 8 waves/CU):
//  - QK^T row-split: each wave holds ALL 4 Q row-tiles in regs, computes S for ONE
//    16-col tile -> 6 kf reads (was 24).
//  - P (64x64) shared in LDS (A-frag chunks); existing vmcnt+barrier orders write->read,
//    plus explicit lgkmcnt(0) before the raw barrier (cross-wave ds_write visibility).
//  - PV dcol-split: each wave owns 3 of 12 d-col tiles for all rows -> 6 vf + 8 pf reads.
//  - Row-sum l via ones-MFMA (B=1.0): lands in C-layout rows, no shuffles.
// Reads: 50 -> 20 per wave-kb. Counted-vmcnt pipeline and staging unchanged.
__global__ __launch_bounds__(256, 2) void k_attn(const u16* __restrict__ q,
                                                 const u16* __restrict__ kmat,
                                                 const u16* __restrict__ vT,
                                                 const float* __restrict__ sqq,
                                                 const float* __restrict__ sqk,
                                                 const float* __restrict__ temp,
                                                 u16* __restrict__ o) {
    __shared__ __align__(16) u16 lK[24 * 512];
    __shared__ __align__(16) u16 lV[24 * 512];
    __shared__ __align__(16) u16 lP[8 * 512];   // P 64x64 bf16, A-frag chunks [rt*2 + kc32]
    float* lcs = (float*)lP;                     // 192 floats, dead before first P write
    const int lin = blockIdx.x;
    const int qb = (lin >> 3) & 15;
    const int bh = (lin & 7) * 4 + (lin >> 7);
    const int b = bh >> 2, h = bh & 3;
    const int tid = threadIdx.x;
    const int lane = tid & 63;
    const int wv = tid >> 6;   // 0..3: QK^T k-col tile; PV d-col group
    const int lr = lane & 15;
    const int lq = lane >> 4;
    const int koff = lq * 8;

    const u16* qbase = q + (size_t)bh * 196608;
    const u16* kbase = kmat + (size_t)bh * 196608;
    const u16* vbase = vT + (size_t)bh * 196608;

    // fused k_scale: cs[dh] = rsqrt(sqq)*rsqrt(sqk)*temperature
    {
        const float tv = temp[bh & 3];
        for (int i = tid; i < 192; i += 256) {
            float rq = 1.f / fmaxf(sqrtf(sqq[bh * 192 + i]), 1e-12f);
            float rk = 1.f / fmaxf(sqrtf(sqk[bh * 192 + i]), 1e-12f);
            lcs[i] = rq * rk * tv;
        }
    }
    __syncthreads();

    // Q fragments: ALL 4 row-tiles of the 64-row block (each wave needs full rows), pre-scaled.
    // swiz read: lane holds row = lane&15, k = ks*32 + (lane>>4)*8 + j
    short8 qf[4][6];
#pragma unroll
    for (int rt = 0; rt < 4; rt++) {
        const int qr16 = qb * 4 + rt;
#pragma unroll
        for (int ks = 0; ks < 6; ks++) {
            short8 raw = *(const short8*)(qbase + ((size_t)(qr16 * 6 + ks)) * 512 + (size_t)lane * 8);
            short8 sc;
#pragma unroll
            for (int j = 0; j < 8; j++) {
                float f = bf2f((u16)raw[j]) * lcs[ks * 32 + koff + j];
                sc[j] = (short)f2bf(f);
            }
            qf[rt][ks] = sc;
        }
    }

    floatx4 lacc[4];       // per-row-tile softmax denominators (ones-MFMA accumulated)
    floatx4 oacc[4][3];    // O tiles: [row-tile][this wave's 3 d-col tiles]
#pragma unroll
    for (int rt = 0; rt < 4; rt++) {
        lacc[rt] = (floatx4){0.f, 0.f, 0.f, 0.f};
#pragma unroll
        for (int i = 0; i < 3; i++) oacc[rt][i] = (floatx4){0.f, 0.f, 0.f, 0.f};
    }
    const short one_bf = (short)0x3F80;  // bf16 1.0
    const short8 ones = {one_bf, one_bf, one_bf, one_bf, one_bf, one_bf, one_bf, one_bf};

    // per-wave staging: 6 K chunks / 6 V chunks (4 waves cover 24 each)
    auto stage_K = [&](int kb2) {
#pragma unroll
        for (int i = 0; i < 6; i++) {
            int ch = i * 4 + wv;  // 0..23
            int ks = ch >> 2, nt = ch & 3;
            const u16* gk = kbase + ((size_t)(kb2 * 4 + nt) * 6 + ks) * 512 + lane * 8;
            gl_lds16(gk, (char*)lK + ch * 1024);
        }
    };
    auto stage_V = [&](int kb2) {
#pragma unroll
        for (int i = 0; i < 6; i++) {
            int ch = i * 4 + wv;  // 0..23
            int ks2 = ch / 12, vt2 = ch - ks2 * 12;
            const u16* gv = vbase + ((size_t)(kb2 * 2 + ks2) * 12 + vt2) * 512 + lane * 8;
            gl_lds16(gv, (char*)lV + ch * 1024);
        }
    };

    // prologue: clean vmem counter (Q loads drained: consumed above), stage K[0]+V[0]
    asm volatile("s_waitcnt vmcnt(0)" ::: "memory");
    stage_K(0);
    stage_V(0);
    asm volatile("s_waitcnt vmcnt(6)" ::: "memory");
    __builtin_amdgcn_s_barrier();

    for (int kb = 0; kb < 16; kb++) {
        // S = Qs * K^T: this wave's 16 k-cols (tile wv) x all 64 q-rows; 6 kf reads
        floatx4 s0[4];
#pragma unroll
        for (int rt = 0; rt < 4; rt++) s0[rt] = (floatx4){0.f, 0.f, 0.f, 0.f};
        __builtin_amdgcn_s_setprio(1);
#pragma unroll
        for (int ks = 0; ks < 6; ks++) {
            short8 kf = *(const short8*)(lK + ((ks * 4 + wv) * 64 + lane) * 8);
#pragma unroll
            for (int rt = 0; rt < 4; rt++)
                s0[rt] = __builtin_amdgcn_mfma_f32_16x16x32_bf16(qf[rt][ks], kf, s0[rt], 0, 0, 0);
        }
        __builtin_amdgcn_s_setprio(0);
        __builtin_amdgcn_s_barrier();     // all waves done reading lK -> safe to overwrite
        if (kb < 15) stage_K(kb + 1);     // K latency hides under softmax + PV

        // exp (no max shift) + P write into shared A-frag image:
        // P[row = rt*16+lq*4+r][k = wv*16+lr] -> chunk rt*2+(wv>>1),
        // off = (((wv&1)*2 + (lr>>3))*16 + lq*4 + r)*8 + (lr&7)
        {
            const int cb = wv >> 1;
            const int offb = (((wv & 1) * 2 + (lr >> 3)) * 16) * 8 + (lr & 7);
#pragma unroll
            for (int rt = 0; rt < 4; rt++) {
                u16* pc = lP + (rt * 2 + cb) * 512 + offb;
#pragma unroll
                for (int r = 0; r < 4; r++)
                    pc[(lq * 4 + r) * 8] = f2bf(__expf(s0[rt][r]));
            }
        }
        // drain ds_writes so partner waves see P after the barrier (raw s_barrier
        // does NOT drain lgkm); vmcnt untouched (counted pipeline intact)
        asm volatile("s_waitcnt lgkmcnt(0)" ::: "memory");
        // wait V[kb] (oldest 6; K[kb+1]'s 6 may remain in flight), all waves
        if (kb < 15) { asm volatile("s_waitcnt vmcnt(6)" ::: "memory"); }
        else         { asm volatile("s_waitcnt vmcnt(0)" ::: "memory"); }
        __builtin_amdgcn_s_barrier();

        // O += P * V on this wave's 3 d-col tiles (all rows); l += P * ones
        __builtin_amdgcn_s_setprio(1);
#pragma unroll
        for (int ks2 = 0; ks2 < 2; ks2++) {
            short8 pf[4];
#pragma unroll
            for (int rt = 0; rt < 4; rt++)
                pf[rt] = *(const short8*)(lP + (rt * 2 + ks2) * 512 + lane * 8);
#pragma unroll
            for (int rt = 0; rt < 4; rt++)
                lacc[rt] = __builtin_amdgcn_mfma_f32_16x16x32_bf16(pf[rt], ones, lacc[rt], 0, 0, 0);
#pragma unroll
            for (int i = 0; i < 3; i++) {
                short8 vf = *(const short8*)(lV + ((ks2 * 12 + wv * 3 + i) * 64 + lane) * 8);
#pragma unroll
                for (int rt = 0; rt < 4; rt++)
                    oacc[rt][i] = __builtin_amdgcn_mfma_f32_16x16x32_bf16(pf[rt], vf, oacc[rt][i], 0, 0, 0);
            }
        }
        __builtin_amdgcn_s_setprio(0);
        __builtin_amdgcn_s_barrier();     // all waves done reading lV (and lP) -> safe to overwrite
        if (kb < 15) {
            stage_V(kb + 1);              // V latency hides under next QK^T + softmax
            asm volatile("s_waitcnt vmcnt(6)" ::: "memory");  // K[kb+1] complete
            __builtin_amdgcn_s_barrier();
        }
    }

    // epilogue: divide by l, stage o tile (64 rows x 192 cols) in lK at block-local swiz
    // offsets (== global swiz restricted to block), then bulk-store 24KB coalesced.
    // each wave writes all rows x its 3 d-col tiles (disjoint columns across waves).
    __syncthreads();   // all waves done with lK
#pragma unroll
    for (int rt = 0; rt < 4; rt++) {
        float inv[4];
#pragma unroll
        for (int r = 0; r < 4; r++) inv[r] = 1.f / lacc[rt][r];
#pragma unroll
        for (int i = 0; i < 3; i++) {
            int col = (wv * 3 + i) * 16 + lr;
            int swb = (col >> 5) * 512 + (((col >> 3) & 3) * 16) * 8 + (col & 7);
#pragma unroll
            for (int r = 0; r < 4; r++) {
                int rowl = rt * 16 + lq * 4 + r;
                lK[(rowl >> 4) * 3072 + swb + (rowl & 15) * 8] = f2bf(oacc[rt][i][r] * inv[r]);
            }
        }
    }
    __syncthreads();
#pragma unroll
    for (int i = 0; i < 6; i++) {
        int u = i * 256 + tid;            // 1536 units of 16B
        int chl = u >> 6, l = u & 63;
        short8 val = *(const short8*)(lK + chl * 512 + l * 8);
        int a = chl / 6, kc = chl - a * 6;
        size_t gaddr = ((size_t)(b * 64 + qb * 4 + a) * 24 + h * 6 + kc) * 512 + l * 8;
        *(short8*)(o + gaddr) = val;
    }
}

// ---------------- LN apply + transpose back + residual: y = LN(o2)^T + x ----------------
// (mu/rstd computed inline from musum/sqsum; o2 is bf16)
__global__ __launch_bounds__(256) void k_lnt(const u16* __restrict__ o2,
                                             const float* __restrict__ musum,
                                             const float* __restrict__ sqsum,
                                             const float* __restrict__ gamma,
                                             const float* __restrict__ beta,
                                             const float* __restrict__ x,
                                             float* __restrict__ y) {
    __shared__ float tile[64][65];
    const int b = blockIdx.z, hw0 = blockIdx.y * 64, cd0 = blockIdx.x * 64;
    const int tid = threadIdx.x;
#pragma unroll
    for (int i = 0; i < 16; i++) {
        int f = i * 256 + tid;
        int hwl = f >> 6, cdl = f & 63;
        int row = b * 1024 + hw0 + hwl;
        float m_ = musum[row] * (1.f / 768.f);
        float var = fmaxf(sqsum[row] * (1.f / 768.f) - m_ * m_, 0.f);
        float rstd = rsqrtf(var + 1e-5f);
        float v = bf2f(o2[(size_t)row * 768 + cd0 + cdl]);
        v = (v - m_) * rstd * gamma[cd0 + cdl] + beta[cd0 + cdl];
        tile[hwl][cdl] = v;
    }
    __syncthreads();
#pragma unroll
    for (int i = 0; i < 16; i++) {
        int f = i * 256 + tid;
        int cdl = f >> 6, hwl = f & 63;
        int cd = cd0 + cdl, c = cd >> 3, d = cd & 7;
        size_t addr = (size_t)((b * 96 + c) * 8 + d) * 1024 + hw0 + hwl;
        y[addr] = tile[hwl][cdl] + x[addr];
    }
}

// ---------------- depthwise 3x3x3 conv: LDS-staged channel + rolling d-window ----------------
// z written in bf16 (halves z traffic; feeds pw conv whose contribution is small)
__global__ __launch_bounds__(256) void k_dw(const float* __restrict__ y,
                                            const float* __restrict__ w,
                                            const float* __restrict__ bias,
                                            u16* __restrict__ z) {
    __shared__ float ly[8192];  // [d][h][w]
    const int bc = blockIdx.x;
    const int c = bc % 96;
    const int tid = threadIdx.x;
    const size_t base = (size_t)bc * 8192;

#pragma unroll
    for (int i = 0; i < 8; i++) {
        int i4 = i * 256 + tid;
        *(float4*)(ly + i4 * 4) = *(const float4*)(y + base + i4 * 4);
    }
    float wt[27];
#pragma unroll
    for (int j = 0; j < 27; j++) wt[j] = w[c * 27 + j];
    const float bv = bias[c];
    __syncthreads();

    const int wcol = tid & 31;
    const int hh = tid >> 5;  // 0..7

    for (int hb = 0; hb < 4; hb++) {
        const int h = hb * 8 + hh;
        float pl[3][9];
        auto loadplane = [&](int dd, float* p) {
#pragma unroll
            for (int kh = 0; kh < 3; kh++) {
                int h2 = h + kh - 1;
                bool hok = (unsigned)h2 < 32u;
                const float* row = ly + dd * 1024 + h2 * 32;
#pragma unroll
                for (int kw = 0; kw < 3; kw++) {
                    int w2 = wcol + kw - 1;
                    bool ok = hok && (unsigned)w2 < 32u;
                    p[kh * 3 + kw] = ok ? row[w2] : 0.f;
                }
            }
        };
#pragma unroll
        for (int j = 0; j < 9; j++) pl[0][j] = 0.f;  // d=-1 plane
        loadplane(0, pl[1]);
#pragma unroll
        for (int d = 0; d < 8; d++) {
            if (d < 7) loadplane(d + 1, pl[2]);
            else {
#pragma unroll
                for (int j = 0; j < 9; j++) pl[2][j] = 0.f;
            }
            float acc = bv;
#pragma unroll
            for (int kd = 0; kd < 3; kd++)
#pragma unroll
                for (int j = 0; j < 9; j++) acc += wt[kd * 9 + j] * pl[kd][j];
            z[base + d * 1024 + h * 32 + wcol] = f2bf(acc);
#pragma unroll
            for (int j = 0; j < 9; j++) { pl[0][j] = pl[1][j]; pl[1][j] = pl[2][j]; }
        }
    }
}

// ---------------- pointwise conv via MFMA: out = y + pw_b + W(96x96) * Z(96 x pos) ----------------
// z is already bf16: staging is a straight u16 copy
__global__ __launch_bounds__(256) void k_pw(const u16* __restrict__ z,
                                            const u16* __restrict__ wbf,   // bf16 96x96 row-major
                                            const float* __restrict__ bias,
                                            float* __restrict__ out) {
    __shared__ __align__(16) u16 lZ[128 * 104];
    __shared__ __align__(16) u16 lW[96 * 104];
    const int tid = threadIdx.x;
    const int lane = tid & 63;
    const int wv = tid >> 6;
    const int lr = lane & 15;
    const int lq = lane >> 4;
    const int koff = lq * 8;

    const int idx = blockIdx.x;
    const int q = idx & 7;
    const int bd = idx >> 3;
    const int b = bd >> 3, d = bd & 7;
    const int pos0 = q * 128;

    for (int i = tid; i < 96 * 96; i += 256) {
        int row = i / 96, col = i - row * 96;
        lW[row * 104 + col] = wbf[i];
    }
    {
        const int pos = tid & 127;
        const int cc0 = (tid >> 7) * 48;
        const size_t gbase = ((size_t)b * 96 * 8 + d) * 1024 + pos0 + pos;
#pragma unroll
        for (int g = 0; g < 6; g++) {
            short8 v;
#pragma unroll
            for (int j = 0; j < 8; j++) {
                int cc = cc0 + g * 8 + j;
                v[j] = (short)z[gbase + (size_t)cc * 8192];
            }
            *(short8*)(lZ + pos * 104 + cc0 + g * 8) = v;
        }
    }
    __syncthreads();

    floatx4 acc[6][2];
#pragma unroll
    for (int m = 0; m < 6; m++)
#pragma unroll
        for (int nt = 0; nt < 2; nt++) acc[m][nt] = (floatx4){0.f, 0.f, 0.f, 0.f};

#pragma unroll
    for (int ks = 0; ks < 3; ks++) {
        short8 bfrg[2];
#pragma unroll
        for (int nt = 0; nt < 2; nt++)
            bfrg[nt] = *(const short8*)(lZ + (wv * 32 + nt * 16 + lr) * 104 + ks * 32 + koff);
#pragma unroll
        for (int m = 0; m < 6; m++) {
            short8 afr = *(const short8*)(lW + (m * 16 + lr) * 104 + ks * 32 + koff);
#pragma unroll
            for (int nt = 0; nt < 2; nt++)
                acc[m][nt] = __builtin_amdgcn_mfma_f32_16x16x32_bf16(afr, bfrg[nt], acc[m][nt], 0, 0, 0);
        }
    }

#pragma unroll
    for (int m = 0; m < 6; m++) {
#pragma unroll
        for (int r = 0; r < 4; r++) {
            int c = m * 16 + lq * 4 + r;
            float bv = bias[c];
            size_t rowbase = ((size_t)(b * 96 + c) * 8 + d) * 1024 + pos0;
#pragma unroll
            for (int nt = 0; nt < 2; nt++) {
                int pos = wv * 32 + nt * 16 + lr;
                size_t a = rowbase + pos;
                out[a] = out[a] + bv + acc[m][nt][r];
            }
        }
    }
}

extern "C" void kernel_launch(void* const* d_in, const int* in_sizes, int n_in,
                              void* d_out, int out_size, void* d_ws, size_t ws_size,
                              hipStream_t stream) {
    (void)in_sizes; (void)n_in; (void)out_size; (void)ws_size;
    const float* x      = (const float*)d_in[0];
    const float* pos    = (const float*)d_in[1];
    const float* qkv_w  = (const float*)d_in[2];
    const float* proj_w = (const float*)d_in[3];
    const float* proj_b = (const float*)d_in[4];
    const float* temp   = (const float*)d_in[5];
    const float* ln_g   = (const float*)d_in[6];
    const float* ln_b   = (const float*)d_in[7];
    const float* dw_w   = (const float*)d_in[8];
    const float* dw_b   = (const float*)d_in[9];
    const float* pw_w   = (const float*)d_in[10];
    const float* pw_b   = (const float*)d_in[11];
    float* out = (float*)d_out;
    char* ws = (char*)d_ws;

    u16* t    = (u16*)(ws + 0);           // swiz A, 12.58MB ; later aliased by o (swiz) and z
    u16* vT   = (u16*)(ws + 12582912);    // v swiz, 12.58MB
    u16* q    = (u16*)(ws + 25165824);    // q swiz (k-layout), 12.58MB ; later o2 bf16 (aliases q)
    u16* kk   = (u16*)(ws + 37748736);    // k swiz, 12.58MB
    u16* wqb  = (u16*)(ws + 50331648);    // qkv_w swiz + proj_w swiz + pw_w, ~4.74MB
    float* sqq   = (float*)(ws + 55175168);  // sqq|sqk|musum|sqsum contiguous, 114688B
    float* sqk   = (float*)(ws + 55199744);
    float* musum = (float*)(ws + 55224320);
    float* sqsum = (float*)(ws + 55257088);
    u16* wpb  = wqb + 2304 * 768;
    u16* wpwb = wqb + 2304 * 768 + 768 * 768;
    u16* o   = t;
    u16* o2  = q;       // proj output bf16, aliases q (dead after attention)
    u16* z   = t;       // depthwise output bf16, aliases t (dead after proj GEMM)
    float* y  = out;

    k_init<<<2836, 256, 0, stream>>>(x, pos, qkv_w, proj_w, pw_w, t, wqb, sqq);
    gemm_bt<0><<<1152, 256, 0, stream>>>(t, wqb, 8192, 2304, 768, q, kk, vT, nullptr, nullptr,
                                         sqq, sqk, nullptr, nullptr);
    k_attn<<<512, 256, 0, stream>>>(q, kk, vT, sqq, sqk, temp, o);
    gemm_bt<1><<<384, 256, 0, stream>>>(o, wpb, 8192, 768, 768, nullptr, nullptr, nullptr, proj_b,
                                        o2, nullptr, nullptr, musum, sqsum);
    k_lnt<<<dim3(12, 16, 8), 256, 0, stream>>>(o2, musum, sqsum, ln_g, ln_b, x, y);
    k_dw<<<768, 256, 0, stream>>>(y, dw_w, dw_b, z);
    k_pw<<<512, 256, 0, stream>>>(z, wpwb, pw_b, out);
}